// Round 1
// 415.747 us; speedup vs baseline: 1.0971x; 1.0971x over previous
//
#include <hip/hip_runtime.h>

// Problem constants
#define BBATCH 4
#define SEQ 4096
#define CC 1024
#define HH 16
#define DD 64
#define TOKENS 16384              // B*N
#define QKV3 3072                 // 3*C

typedef __attribute__((ext_vector_type(8))) short short8;
typedef __attribute__((ext_vector_type(4))) float floatx4;

// bf16 helpers (RNE)
__device__ __forceinline__ unsigned short f2bf(float x) {
    unsigned int u = __float_as_uint(x);
    u += 0x7fff + ((u >> 16) & 1);
    return (unsigned short)(u >> 16);
}
__device__ __forceinline__ float bf2f(unsigned short h) {
    return __uint_as_float((unsigned int)h << 16);
}

__device__ __forceinline__ void gload_lds16(const void* g, void* l) {
    __builtin_amdgcn_global_load_lds(
        (const __attribute__((address_space(1))) unsigned int*)g,
        (__attribute__((address_space(3))) unsigned int*)l, 16, 0, 0);
}

// ---------------------------------------------------------------------------
// fp32 -> bf16 convert (x)
// ---------------------------------------------------------------------------
__global__ __launch_bounds__(256) void cvt_bf16_kernel(
    const float* __restrict__ X, unsigned short* __restrict__ Y, long n4)
{
    long i = (long)blockIdx.x * 256 + threadIdx.x;
    if (i >= n4) return;
    float4 v = *reinterpret_cast<const float4*>(&X[i * 4]);
    ushort4 h;
    h.x = f2bf(v.x); h.y = f2bf(v.y); h.z = f2bf(v.z); h.w = f2bf(v.w);
    *reinterpret_cast<ushort4*>(&Y[i * 4]) = h;
}

// ---------------------------------------------------------------------------
// Transpose W[K,N] -> T[N,K] bf16. 32x32 tiles, 256 threads.
// ---------------------------------------------------------------------------
__global__ __launch_bounds__(256) void transpose_bf16_kernel(
    const float* __restrict__ W, int K, int N, unsigned short* __restrict__ T)
{
    __shared__ unsigned short Lh[32][36];
    const int k0 = blockIdx.y * 32, n0 = blockIdx.x * 32;
    const int t = threadIdx.x;
    const int r = t >> 3, c4 = (t & 7) * 4;

    float4 w = *reinterpret_cast<const float4*>(&W[(size_t)(k0 + r) * N + n0 + c4]);
    Lh[r][c4 + 0] = f2bf(w.x);
    Lh[r][c4 + 1] = f2bf(w.y);
    Lh[r][c4 + 2] = f2bf(w.z);
    Lh[r][c4 + 3] = f2bf(w.w);
    __syncthreads();

    const int rn = t >> 3, ck = (t & 7) * 4;
    ushort4 h4;
    h4.x = Lh[ck + 0][rn]; h4.y = Lh[ck + 1][rn];
    h4.z = Lh[ck + 2][rn]; h4.w = Lh[ck + 3][rn];
    *reinterpret_cast<ushort4*>(&T[(size_t)(n0 + rn) * K + k0 + ck]) = h4;
}

// ---------------------------------------------------------------------------
// 256x256 8-phase bf16 GEMM (HK-style template, plain HIP).
//   BM=BN=256, BK=64, 512 threads = 8 waves (2M x 4N), per-wave 128x64 out.
//   LDS 128 KiB: 2 dbuf x (A 256x64 + B 256x64) bf16.
//   T2: XOR swizzle byte ^= ((row&7)<<4); gload_lds writes linear, so the
//       inverse swizzle is applied to the per-lane GLOBAL source address.
//   T3/T4: 8 phases / 2 K-tiles per iter, one half-tile staged per phase,
//       vmcnt(2) only at phases 4 & 8 (8 older loads drain, 2 stay in flight).
//   T5: setprio(1) around each 16-MFMA cluster.
//   T1: XCD-bijective blockIdx swizzle (nwg % 8 == 0 for both grids).
// MODE 0: out GEMM (per-batch WeffT, fp32 store + bias).
// MODE 1: QKV GEMM (bf16 scatter to Q/K/V + bias).
// K is fixed at 1024 -> 16 K-tiles -> 8 iterations.
// ---------------------------------------------------------------------------
template <int MODE>
__global__ __launch_bounds__(512) void gemm256_bf16_kernel(
    const unsigned short* __restrict__ A, int lda,
    const unsigned short* __restrict__ Bt, int ldb,
    const float* __restrict__ bias,
    float* __restrict__ Cf, int ldc,
    unsigned short* __restrict__ Qo, unsigned short* __restrict__ Ko,
    unsigned short* __restrict__ Vo)
{
    // buf0: A @ [0,16384), B @ [16384,32768); buf1: +32768   (shorts)
    __shared__ unsigned short smem[65536];   // 128 KiB

    const int t = threadIdx.x;
    const int wave = t >> 6, lane = t & 63;

    // T1: XCD-bijective swizzle
    const int gx = gridDim.x;
    const int nwg = gx * gridDim.y;
    const int id0 = blockIdx.y * gx + blockIdx.x;
    const int cpx = nwg >> 3;
    const int swzid = (id0 & 7) * cpx + (id0 >> 3);
    const int bx = swzid % gx, by = swzid / gx;

    const int row0 = by * 256, col0 = bx * 256;
    const int wave_m = wave >> 2, wave_n = wave & 3;

    const unsigned short* Bp = Bt;
    if (MODE == 0) Bp += ((size_t)(row0 >> 12)) << 20;   // per-batch WeffT

    // fragment-read lane constants (swizzled LDS addressing, in shorts)
    const int fr  = lane & 15;
    const int fqb = (lane >> 4) << 4;                 // 16B chunk byte-offset
    const int sm  = (fr & 7) << 4;
    const int ck0 = ((0  + fqb) ^ sm) >> 1;           // k-slice 0 col (shorts)
    const int ck1 = ((64 + fqb) ^ sm) >> 1;           // k-slice 1 col (shorts)
    const int aRow = (wave_m * 128 + fr) * 64;        // within A region
    const int bRow = (wave_n * 64 + fr) * 64;         // within B region

    // staging lane constants: linear LDS dest, inverse-swizzled global source
    int srow[2], scol[2];
#pragma unroll
    for (int e = 0; e < 2; e++) {
        const int P  = (wave << 10) + (lane << 4) + (e << 13);  // byte in half
        const int r  = P >> 7;
        const int pc = P & 127;
        srow[e] = r;
        scol[e] = (pc ^ ((r & 7) << 4)) >> 1;         // bf16 col within 64
    }

    // stage one 128x64 half-tile: part = isB*2 + half
    auto STAGE_PART = [&](int kt, int buf, int part) {
        const int isB = part >> 1, half = part & 1;
        const unsigned short* p = isB ? Bp : A;
        const int r0 = isB ? col0 : row0;
        const int ld = isB ? ldb : lda;
        const int ldsOff = buf * 32768 + isB * 16384 + half * 8192 + wave * 512;
#pragma unroll
        for (int e = 0; e < 2; e++)
            gload_lds16(&p[(size_t)(r0 + half * 128 + srow[e]) * ld
                           + ((kt & 15) << 6) + scol[e]],
                        &smem[ldsOff + e * 4096]);
    };

    floatx4 acc[8][4];
#pragma unroll
    for (int i = 0; i < 8; i++)
#pragma unroll
        for (int j = 0; j < 4; j++) acc[i][j] = (floatx4)0.0f;

    short8 a[4][2], bl[2][2], bh[2][2];

#define RDA(BUF, IH)                                                          \
    _Pragma("unroll") for (int ii = 0; ii < 4; ii++) {                        \
        a[ii][0] = *reinterpret_cast<const short8*>(                          \
            &smem[(BUF) * 32768 + aRow + ((IH) * 64 + ii * 16) * 64 + ck0]);  \
        a[ii][1] = *reinterpret_cast<const short8*>(                          \
            &smem[(BUF) * 32768 + aRow + ((IH) * 64 + ii * 16) * 64 + ck1]);  \
    }
#define RDB(BUF, JH, DST)                                                     \
    _Pragma("unroll") for (int jj = 0; jj < 2; jj++) {                        \
        DST[jj][0] = *reinterpret_cast<const short8*>(                        \
            &smem[(BUF) * 32768 + 16384 + bRow + ((JH) * 32 + jj * 16) * 64 + ck0]); \
        DST[jj][1] = *reinterpret_cast<const short8*>(                        \
            &smem[(BUF) * 32768 + 16384 + bRow + ((JH) * 32 + jj * 16) * 64 + ck1]); \
    }
#define MFMA_Q(IH, JH, BB)                                                    \
    __builtin_amdgcn_s_setprio(1);                                            \
    _Pragma("unroll") for (int ii = 0; ii < 4; ii++)                          \
    _Pragma("unroll") for (int jj = 0; jj < 2; jj++) {                        \
        acc[(IH)*4+ii][(JH)*2+jj] = __builtin_amdgcn_mfma_f32_16x16x32_bf16(  \
            a[ii][0], BB[jj][0], acc[(IH)*4+ii][(JH)*2+jj], 0, 0, 0);         \
        acc[(IH)*4+ii][(JH)*2+jj] = __builtin_amdgcn_mfma_f32_16x16x32_bf16(  \
            a[ii][1], BB[jj][1], acc[(IH)*4+ii][(JH)*2+jj], 0, 0, 0);         \
    }                                                                         \
    __builtin_amdgcn_s_setprio(0);
#define BARRIER __builtin_amdgcn_s_barrier()
#define WAIT_LGKM asm volatile("s_waitcnt lgkmcnt(0)" ::: "memory")
#define WAIT_VM2  asm volatile("s_waitcnt vmcnt(2)" ::: "memory")

    // 4 phases of one K-tile in buffer CUR; stages: P1-P3 finish tile TN into
    // OTH, P4 starts tile TX into CUR (CUR's reads completed at P3).
#define KTILE(CUR, OTH, TN, TX)                                               \
    {                                                                         \
        RDA(CUR, 0); RDB(CUR, 0, bl);                                         \
        STAGE_PART(TN, OTH, 1);                                               \
        BARRIER; WAIT_LGKM; MFMA_Q(0, 0, bl); BARRIER;                        \
        RDB(CUR, 1, bh);                                                      \
        STAGE_PART(TN, OTH, 2);                                               \
        BARRIER; WAIT_LGKM; MFMA_Q(0, 1, bh); BARRIER;                        \
        RDA(CUR, 1);                                                          \
        STAGE_PART(TN, OTH, 3);                                               \
        BARRIER; WAIT_LGKM; MFMA_Q(1, 1, bh); BARRIER;                        \
        STAGE_PART(TX, CUR, 0);                                               \
        WAIT_VM2;                                                             \
        BARRIER;                                                              \
        MFMA_Q(1, 0, bl);                                                     \
        BARRIER;                                                              \
    }

    // prologue: K0 fully into buf0, K1:A0 into buf1; wait K0, keep 2 in flight
    STAGE_PART(0, 0, 0); STAGE_PART(0, 0, 1);
    STAGE_PART(0, 0, 2); STAGE_PART(0, 0, 3);
    STAGE_PART(1, 1, 0);
    WAIT_VM2;
    BARRIER;

#pragma unroll 1
    for (int it = 0; it < 8; it++) {
        const int t1 = 2 * it + 1, t2 = 2 * it + 2, t3 = 2 * it + 3;
        KTILE(0, 1, t1, t2);      // compute K-tile 2*it   (buf0)
        KTILE(1, 0, t2, t3);      // compute K-tile 2*it+1 (buf1)
    }

#undef KTILE
#undef WAIT_VM2
#undef WAIT_LGKM
#undef BARRIER
#undef MFMA_Q
#undef RDB
#undef RDA

    // epilogue. C/D layout: col = lane&15, row = (lane>>4)*4 + reg [m89]
    const int cn = lane & 15, cq = (lane >> 4) * 4;
    if (MODE == 0) {
#pragma unroll
        for (int j = 0; j < 4; j++) {
            const int col = col0 + wave_n * 64 + j * 16 + cn;
            const float bv = bias[col];
#pragma unroll
            for (int i = 0; i < 8; i++)
#pragma unroll
                for (int r = 0; r < 4; r++) {
                    const int row = row0 + wave_m * 128 + i * 16 + cq + r;
                    Cf[(size_t)row * ldc + col] = acc[i][j][r] + bv;
                }
        }
    } else {
        unsigned short* outp = (bx < 4) ? Qo : ((bx < 8) ? Ko : Vo);
        const int f0 = col0 & 1023;
#pragma unroll
        for (int j = 0; j < 4; j++) {
            const int colg = col0 + wave_n * 64 + j * 16 + cn;
            const int f = f0 + wave_n * 64 + j * 16 + cn;
            const float bv = bias[colg];
#pragma unroll
            for (int i = 0; i < 8; i++)
#pragma unroll
                for (int r = 0; r < 4; r++) {
                    const int row = row0 + wave_m * 128 + i * 16 + cq + r;
                    outp[(size_t)row * CC + f] = f2bf(acc[i][j][r] + bv);
                }
        }
    }
}

// ---------------------------------------------------------------------------
// Q softmax over head_dim (64), bf16 in/out. 16 lanes per head-row.
// ---------------------------------------------------------------------------
__global__ __launch_bounds__(256) void q_softmax_kernel(unsigned short* __restrict__ Q)
{
    const int t = threadIdx.x;
    const long row = (long)blockIdx.x * 16 + (t >> 4);   // (token*H + h), < 262144
    const int d4 = (t & 15) * 4;
    ushort4 hv = *reinterpret_cast<const ushort4*>(&Q[row * 64 + d4]);
    float v0 = bf2f(hv.x), v1 = bf2f(hv.y), v2 = bf2f(hv.z), v3 = bf2f(hv.w);
    float m = fmaxf(fmaxf(v0, v1), fmaxf(v2, v3));
#pragma unroll
    for (int s = 8; s > 0; s >>= 1) m = fmaxf(m, __shfl_xor(m, s));
    float e0 = __expf(v0 - m), e1 = __expf(v1 - m), e2 = __expf(v2 - m), e3 = __expf(v3 - m);
    float sum = e0 + e1 + e2 + e3;
#pragma unroll
    for (int s = 8; s > 0; s >>= 1) sum += __shfl_xor(sum, s);
    const float inv = 1.0f / sum;
    ushort4 o;
    o.x = f2bf(e0 * inv); o.y = f2bf(e1 * inv); o.z = f2bf(e2 * inv); o.w = f2bf(e3 * inv);
    *reinterpret_cast<ushort4*>(&Q[row * 64 + d4]) = o;
}

// ---------------------------------------------------------------------------
// Single-pass K/V context: ctx_u[bh,d,e] += sum_n exp(K[n,d]) * V[n,e]
//                          csum[bh,d]   += sum_n exp(K[n,d])
// ---------------------------------------------------------------------------
__global__ __launch_bounds__(256) void kv_ctx_kernel(
    const unsigned short* __restrict__ Km, const unsigned short* __restrict__ Vm,
    float* __restrict__ ctx, float* __restrict__ csum)
{
    const int bh = blockIdx.x, ch = blockIdx.y;
    const int b = bh >> 4, h = bh & 15;
    const int t = threadIdx.x;

    __shared__ float Ks[32][68];
    __shared__ float Vs[32][68];
    __shared__ float cred[4][64];

    const int d0 = (t >> 4) * 4, e0 = (t & 15) * 4;
    float acc[4][4];
#pragma unroll
    for (int i = 0; i < 4; i++)
#pragma unroll
        for (int j = 0; j < 4; j++) acc[i][j] = 0.0f;
    float csacc = 0.0f;
    const int dc = t & 63, rq = (t >> 6) * 8;

    const size_t base = (size_t)(b * SEQ + ch * 256) * CC + (size_t)h * 64;

    for (int n0 = 0; n0 < 256; n0 += 32) {
        __syncthreads();
#pragma unroll
        for (int l = 0; l < 2; l++) {
            const int idx = t + l * 256;
            const int r = idx >> 4, c4 = (idx & 15) * 4;
            ushort4 kv = *reinterpret_cast<const ushort4*>(&Km[base + (size_t)(n0 + r) * CC + c4]);
            ushort4 vv = *reinterpret_cast<const ushort4*>(&Vm[base + (size_t)(n0 + r) * CC + c4]);
            float4 kf;
            kf.x = __expf(bf2f(kv.x));
            kf.y = __expf(bf2f(kv.y));
            kf.z = __expf(bf2f(kv.z));
            kf.w = __expf(bf2f(kv.w));
            float4 vf = {bf2f(vv.x), bf2f(vv.y), bf2f(vv.z), bf2f(vv.w)};
            *reinterpret_cast<float4*>(&Ks[r][c4]) = kf;
            *reinterpret_cast<float4*>(&Vs[r][c4]) = vf;
        }
        __syncthreads();

#pragma unroll
        for (int r = 0; r < 8; r++) csacc += Ks[rq + r][dc];

#pragma unroll 8
        for (int n = 0; n < 32; n++) {
            float4 a = *reinterpret_cast<const float4*>(&Ks[n][d0]);
            float4 v4 = *reinterpret_cast<const float4*>(&Vs[n][e0]);
            float a4[4] = {a.x, a.y, a.z, a.w};
            float b4[4] = {v4.x, v4.y, v4.z, v4.w};
#pragma unroll
            for (int i = 0; i < 4; i++)
#pragma unroll
                for (int j = 0; j < 4; j++)
                    acc[i][j] += a4[i] * b4[j];
        }
    }

    __syncthreads();
    cred[t >> 6][dc] = csacc;
    __syncthreads();
    if (t < 64)
        atomicAdd(&csum[(size_t)bh * 64 + t],
                  cred[0][t] + cred[1][t] + cred[2][t] + cred[3][t]);

#pragma unroll
    for (int i = 0; i < 4; i++)
#pragma unroll
        for (int j = 0; j < 4; j++)
            atomicAdd(&ctx[((size_t)bh * 64 + d0 + i) * 64 + e0 + j], acc[i][j]);
}

// ---------------------------------------------------------------------------
// W_eff build: WeffT[b][n][h*64+d] = f2bf( (1/csum[bh,d]) *
//                                     sum_e ctx_u[b,h,d,e] * Wp[h*64+e, n] )
// ---------------------------------------------------------------------------
__global__ __launch_bounds__(256) void weff_kernel(
    const float* __restrict__ ctx, const float* __restrict__ csum,
    const float* __restrict__ Wp, unsigned short* __restrict__ WeffT)
{
    const int bh = blockIdx.x, nc = blockIdx.y;
    const int b = bh >> 4, h = bh & 15;
    const int t = threadIdx.x;

    __shared__ float ctxs[64 * 64];
    __shared__ float cinvs[64];
#pragma unroll
    for (int l = 0; l < 16; l++)
        ctxs[t + l * 256] = ctx[(size_t)bh * 4096 + t + l * 256];
    if (t < 64) cinvs[t] = 1.0f / csum[(size_t)bh * 64 + t];
    __syncthreads();

    const int n = nc * 128 + (t & 127);
    const int dg = (t >> 7) * 32;

    float acc[32];
#pragma unroll
    for (int d = 0; d < 32; d++) acc[d] = 0.0f;

    for (int e = 0; e < 64; e++) {
        const float w = Wp[(size_t)(h * 64 + e) * CC + n];
#pragma unroll
        for (int d = 0; d < 32; d++)
            acc[d] += ctxs[(dg + d) * 64 + e] * w;
    }

    const size_t obase = ((size_t)b << 20) + (size_t)n * CC + h * 64 + dg;
#pragma unroll
    for (int d = 0; d < 32; d += 2) {
        ushort2 o;
        o.x = f2bf(acc[d] * cinvs[dg + d]);
        o.y = f2bf(acc[d + 1] * cinvs[dg + d + 1]);
        *reinterpret_cast<ushort2*>(&WeffT[obase + d]) = o;
    }
}

// ---------------------------------------------------------------------------
extern "C" void kernel_launch(void* const* d_in, const int* in_sizes, int n_in,
                              void* d_out, int out_size, void* d_ws, size_t ws_size,
                              hipStream_t stream)
{
    const float* x      = (const float*)d_in[0];
    const float* W_qkv  = (const float*)d_in[1];
    const float* b_qkv  = (const float*)d_in[2];
    const float* W_proj = (const float*)d_in[3];
    const float* b_proj = (const float*)d_in[4];
    float* out = (float*)d_out;

    unsigned short* Qm  = (unsigned short*)d_ws;               // [16384,1024] bf16
    unsigned short* Km  = Qm + (size_t)TOKENS * CC;
    unsigned short* Vm  = Km + (size_t)TOKENS * CC;
    unsigned short* xb  = Vm + (size_t)TOKENS * CC;            // x bf16
    unsigned short* wqT = xb + (size_t)TOKENS * CC;            // [3072,1024]
    unsigned short* WeffT = wqT + (size_t)QKV3 * CC;           // [4,1024,1024] bf16
    float* ctx  = (float*)(WeffT + (size_t)BBATCH * CC * CC);  // [64,64,64] fp32
    float* csum = ctx + (size_t)64 * 64 * 64;                  // [64,64]

    hipMemsetAsync(ctx, 0, ((size_t)64 * 64 * 64 + 64 * 64) * sizeof(float), stream);

    // 0) x -> bf16; W_qkv -> bf16 transposed
    cvt_bf16_kernel<<<(TOKENS * CC / 4 + 255) / 256, 256, 0, stream>>>(
        x, xb, (long)TOKENS * CC / 4);
    transpose_bf16_kernel<<<dim3(QKV3 / 32, CC / 32), 256, 0, stream>>>(
        W_qkv, CC, QKV3, wqT);

    // 1) QKV GEMM -> Q / K / V bf16 (256^2 8-phase)
    gemm256_bf16_kernel<1><<<dim3(QKV3 / 256, TOKENS / 256), 512, 0, stream>>>(
        xb, CC, wqT, CC, b_qkv, (float*)nullptr, 0, Qm, Km, Vm);

    // 2) softmax(Q) over head_dim
    q_softmax_kernel<<<(TOKENS * HH) / 16, 256, 0, stream>>>(Qm);

    // 3) single-pass exp(K)/V -> ctx_u + csum
    kv_ctx_kernel<<<dim3(BBATCH * HH, 16), 256, 0, stream>>>(Km, Vm, ctx, csum);

    // 4) effective projection weights per batch (applies 1/csum)
    weff_kernel<<<dim3(BBATCH * HH, 8), 256, 0, stream>>>(ctx, csum, W_proj, WeffT);

    // 5) out = Qhat @ WeffT[batch] + b_proj (256^2 8-phase)
    gemm256_bf16_kernel<0><<<dim3(CC / 256, TOKENS / 256), 512, 0, stream>>>(
        Qm, CC, WeffT, CC, b_proj, out, CC, nullptr, nullptr, nullptr);
}

// Round 2
// 413.223 us; speedup vs baseline: 1.1038x; 1.0061x over previous
//
#include <hip/hip_runtime.h>

// Problem constants
#define BBATCH 4
#define SEQ 4096
#define CC 1024
#define HH 16
#define DD 64
#define TOKENS 16384              // B*N
#define QKV3 3072                 // 3*C

typedef __attribute__((ext_vector_type(8))) short short8;
typedef __attribute__((ext_vector_type(4))) float floatx4;

// bf16 helpers (RNE)
__device__ __forceinline__ unsigned short f2bf(float x) {
    unsigned int u = __float_as_uint(x);
    u += 0x7fff + ((u >> 16) & 1);
    return (unsigned short)(u >> 16);
}
__device__ __forceinline__ float bf2f(unsigned short h) {
    return __uint_as_float((unsigned int)h << 16);
}

__device__ __forceinline__ void gload_lds16(const void* g, void* l) {
    __builtin_amdgcn_global_load_lds(
        (const __attribute__((address_space(1))) unsigned int*)g,
        (__attribute__((address_space(3))) unsigned int*)l, 16, 0, 0);
}

// ---------------------------------------------------------------------------
// fp32 -> bf16 convert (x)
// ---------------------------------------------------------------------------
__global__ __launch_bounds__(256) void cvt_bf16_kernel(
    const float* __restrict__ X, unsigned short* __restrict__ Y, long n4)
{
    long i = (long)blockIdx.x * 256 + threadIdx.x;
    if (i >= n4) return;
    float4 v = *reinterpret_cast<const float4*>(&X[i * 4]);
    ushort4 h;
    h.x = f2bf(v.x); h.y = f2bf(v.y); h.z = f2bf(v.z); h.w = f2bf(v.w);
    *reinterpret_cast<ushort4*>(&Y[i * 4]) = h;
}

// ---------------------------------------------------------------------------
// Transpose W[K,N] -> T[N,K] bf16. 32x32 tiles, 256 threads.
// ---------------------------------------------------------------------------
__global__ __launch_bounds__(256) void transpose_bf16_kernel(
    const float* __restrict__ W, int K, int N, unsigned short* __restrict__ T)
{
    __shared__ unsigned short Lh[32][36];
    const int k0 = blockIdx.y * 32, n0 = blockIdx.x * 32;
    const int t = threadIdx.x;
    const int r = t >> 3, c4 = (t & 7) * 4;

    float4 w = *reinterpret_cast<const float4*>(&W[(size_t)(k0 + r) * N + n0 + c4]);
    Lh[r][c4 + 0] = f2bf(w.x);
    Lh[r][c4 + 1] = f2bf(w.y);
    Lh[r][c4 + 2] = f2bf(w.z);
    Lh[r][c4 + 3] = f2bf(w.w);
    __syncthreads();

    const int rn = t >> 3, ck = (t & 7) * 4;
    ushort4 h4;
    h4.x = Lh[ck + 0][rn]; h4.y = Lh[ck + 1][rn];
    h4.z = Lh[ck + 2][rn]; h4.w = Lh[ck + 3][rn];
    *reinterpret_cast<ushort4*>(&T[(size_t)(n0 + rn) * K + k0 + ck]) = h4;
}

// ---------------------------------------------------------------------------
// 256x256 8-phase bf16 GEMM (HK-style template, plain HIP).
//   BM=BN=256, BK=64, 512 threads = 8 waves (2M x 4N), per-wave 128x64 out.
//   LDS 128 KiB: 2 dbuf x (A 256x64 + B 256x64) bf16, XOR-swizzled rows
//   (inverse swizzle applied on the per-lane GLOBAL source of gload_lds).
//   Pipeline (R2 fix): KTILE(t) computes from CUR and stages tile t+2 into
//   CUR as regions are freed (B halves at P3 -- B fully read by end of P2;
//   A halves at P4 -- A fully read by end of P3). Tile t+1 was therefore
//   fully ISSUED one whole K-tile (4 phases) before its vmcnt(8) wait at P4
//   -> load latency hidden (was: 1-phase distance = near-drain, MfmaUtil 33%).
//   vmcnt(8) once per K-tile, never lower in the main loop.
//   T5: setprio(1) around each 16-MFMA cluster. T1: XCD-bijective swizzle.
// MODE 0: out GEMM (per-batch WeffT, fp32 direct store + bias: stores are
//         already 64B-line-complete per 16 lanes).
// MODE 1: QKV GEMM. Epilogue: acc+bias -> LDS (256x256 bf16 = exactly 128KiB,
//         16B-chunk XOR swizzle), coalesced ushort8 read-back + store; the
//         read-back thread holds 2 complete heads -> Q softmax fused here
//         (thread-local, no shuffles), q_softmax kernel deleted.
// K fixed at 1024 -> 16 K-tiles.
// ---------------------------------------------------------------------------
template <int MODE>
__global__ __launch_bounds__(512) void gemm256_bf16_kernel(
    const unsigned short* __restrict__ A, int lda,
    const unsigned short* __restrict__ Bt, int ldb,
    const float* __restrict__ bias,
    float* __restrict__ Cf, int ldc,
    unsigned short* __restrict__ Qo, unsigned short* __restrict__ Ko,
    unsigned short* __restrict__ Vo)
{
    // buf0: A @ [0,16384), B @ [16384,32768); buf1: +32768   (shorts)
    __shared__ unsigned short smem[65536];   // 128 KiB

    const int t = threadIdx.x;
    const int wave = t >> 6, lane = t & 63;

    // T1: XCD-bijective swizzle (nwg % 8 == 0 for both grids)
    const int gx = gridDim.x;
    const int nwg = gx * gridDim.y;
    const int id0 = blockIdx.y * gx + blockIdx.x;
    const int cpx = nwg >> 3;
    const int swzid = (id0 & 7) * cpx + (id0 >> 3);
    const int bx = swzid % gx, by = swzid / gx;

    const int row0 = by * 256, col0 = bx * 256;
    const int wave_m = wave >> 2, wave_n = wave & 3;

    const unsigned short* Bp = Bt;
    if (MODE == 0) Bp += ((size_t)(row0 >> 12)) << 20;   // per-batch WeffT

    // fragment-read lane constants (swizzled LDS addressing, in shorts)
    const int fr  = lane & 15;
    const int fqb = (lane >> 4) << 4;                 // 16B chunk byte-offset
    const int sm  = (fr & 7) << 4;
    const int ck0 = ((0  + fqb) ^ sm) >> 1;           // k-slice 0 col (shorts)
    const int ck1 = ((64 + fqb) ^ sm) >> 1;           // k-slice 1 col (shorts)
    const int aRow = (wave_m * 128 + fr) * 64;        // within A region
    const int bRow = (wave_n * 64 + fr) * 64;         // within B region

    // staging lane constants: linear LDS dest, inverse-swizzled global source
    int srow[2], scol[2];
#pragma unroll
    for (int e = 0; e < 2; e++) {
        const int P  = (wave << 10) + (lane << 4) + (e << 13);  // byte in half
        const int r  = P >> 7;
        const int pc = P & 127;
        srow[e] = r;
        scol[e] = (pc ^ ((r & 7) << 4)) >> 1;         // bf16 col within 64
    }

    // stage one 128x64 half-tile: part = isB*2 + half
    auto STAGE_PART = [&](int kt, int buf, int part) {
        const int isB = part >> 1, half = part & 1;
        const unsigned short* p = isB ? Bp : A;
        const int r0 = isB ? col0 : row0;
        const int ld = isB ? ldb : lda;
        const int ldsOff = buf * 32768 + isB * 16384 + half * 8192 + wave * 512;
#pragma unroll
        for (int e = 0; e < 2; e++)
            gload_lds16(&p[(size_t)(r0 + half * 128 + srow[e]) * ld
                           + ((kt & 15) << 6) + scol[e]],
                        &smem[ldsOff + e * 4096]);
    };

    floatx4 acc[8][4];
#pragma unroll
    for (int i = 0; i < 8; i++)
#pragma unroll
        for (int j = 0; j < 4; j++) acc[i][j] = (floatx4)0.0f;

    short8 a[4][2], bl[2][2], bh[2][2];

#define RDA(BUF, IH)                                                          \
    _Pragma("unroll") for (int ii = 0; ii < 4; ii++) {                        \
        a[ii][0] = *reinterpret_cast<const short8*>(                          \
            &smem[(BUF) * 32768 + aRow + ((IH) * 64 + ii * 16) * 64 + ck0]);  \
        a[ii][1] = *reinterpret_cast<const short8*>(                          \
            &smem[(BUF) * 32768 + aRow + ((IH) * 64 + ii * 16) * 64 + ck1]);  \
    }
#define RDB(BUF, JH, DST)                                                     \
    _Pragma("unroll") for (int jj = 0; jj < 2; jj++) {                        \
        DST[jj][0] = *reinterpret_cast<const short8*>(                        \
            &smem[(BUF) * 32768 + 16384 + bRow + ((JH) * 32 + jj * 16) * 64 + ck0]); \
        DST[jj][1] = *reinterpret_cast<const short8*>(                        \
            &smem[(BUF) * 32768 + 16384 + bRow + ((JH) * 32 + jj * 16) * 64 + ck1]); \
    }
#define MFMA_Q(IH, JH, BB)                                                    \
    __builtin_amdgcn_s_setprio(1);                                            \
    _Pragma("unroll") for (int ii = 0; ii < 4; ii++)                          \
    _Pragma("unroll") for (int jj = 0; jj < 2; jj++) {                        \
        acc[(IH)*4+ii][(JH)*2+jj] = __builtin_amdgcn_mfma_f32_16x16x32_bf16(  \
            a[ii][0], BB[jj][0], acc[(IH)*4+ii][(JH)*2+jj], 0, 0, 0);         \
        acc[(IH)*4+ii][(JH)*2+jj] = __builtin_amdgcn_mfma_f32_16x16x32_bf16(  \
            a[ii][1], BB[jj][1], acc[(IH)*4+ii][(JH)*2+jj], 0, 0, 0);         \
    }                                                                         \
    __builtin_amdgcn_s_setprio(0);
#define BARRIER __builtin_amdgcn_s_barrier()
#define WAIT_LGKM asm volatile("s_waitcnt lgkmcnt(0)" ::: "memory")
#define WAIT_VM8  asm volatile("s_waitcnt vmcnt(8)" ::: "memory")

    // Compute tile in CUR; stage tile TS (same parity, t+2) into CUR.
    //  P1: read A0+B0           (no region of CUR free yet)
    //  P2: read B1              (no region free: A read completes only at P3)
    //  P3: read A1; stage TS:B0,B1  (all B reads done before P2's 2nd barrier)
    //  P4: stage TS:A0,A1           (all A reads done before P3's 2nd barrier)
    //      vmcnt(8): drains prev KTILE's 8 loads -> other buffer (tile t+1)
    //      fully resident; TS's 8 stay in flight.
#define KTILE(CUR, TS)                                                        \
    {                                                                         \
        RDA(CUR, 0); RDB(CUR, 0, bl);                                         \
        BARRIER; WAIT_LGKM; MFMA_Q(0, 0, bl); BARRIER;                        \
        RDB(CUR, 1, bh);                                                      \
        BARRIER; WAIT_LGKM; MFMA_Q(0, 1, bh); BARRIER;                        \
        RDA(CUR, 1);                                                          \
        STAGE_PART(TS, CUR, 2); STAGE_PART(TS, CUR, 3);                       \
        BARRIER; WAIT_LGKM; MFMA_Q(1, 1, bh); BARRIER;                        \
        STAGE_PART(TS, CUR, 0); STAGE_PART(TS, CUR, 1);                       \
        WAIT_VM8;                                                             \
        BARRIER;                                                              \
        MFMA_Q(1, 0, bl);                                                     \
        BARRIER;                                                              \
    }

    // prologue: tiles 0 and 1 fully staged; wait tile0 (8 of tile1 in flight)
    STAGE_PART(0, 0, 0); STAGE_PART(0, 0, 1);
    STAGE_PART(0, 0, 2); STAGE_PART(0, 0, 3);
    STAGE_PART(1, 1, 0); STAGE_PART(1, 1, 1);
    STAGE_PART(1, 1, 2); STAGE_PART(1, 1, 3);
    WAIT_VM8;
    BARRIER;

#pragma unroll 1
    for (int it = 0; it < 8; it++) {
        KTILE(0, (2 * it + 2) & 15);   // compute K-tile 2it   (buf0)
        KTILE(1, (2 * it + 3) & 15);   // compute K-tile 2it+1 (buf1)
    }

#undef KTILE
#undef WAIT_VM8
#undef WAIT_LGKM
#undef BARRIER
#undef MFMA_Q
#undef RDB
#undef RDA

    // ---- epilogue ----
    // C/D layout: col = lane&15, row = (lane>>4)*4 + reg [m89]
    const int cn = lane & 15, cq = (lane >> 4) * 4;

    if (MODE == 0) {
        // fp32 direct store: 16 lanes cover a full 64B line -> no amplification
#pragma unroll
        for (int j = 0; j < 4; j++) {
            const int col = col0 + wave_n * 64 + j * 16 + cn;
            const float bv = bias[col];
#pragma unroll
            for (int i = 0; i < 8; i++)
#pragma unroll
                for (int r = 0; r < 4; r++) {
                    const int row = row0 + wave_m * 128 + i * 16 + cq + r;
                    Cf[(size_t)row * ldc + col] = acc[i][j][r] + bv;
                }
        }
        return;
    }

    // MODE 1: LDS-staged coalesced epilogue with fused Q softmax.
    // Drain in-flight gload_lds (wrapped tail prefetch) before reusing smem.
    __syncthreads();   // emits s_waitcnt vmcnt(0) lgkmcnt(0) + s_barrier

    // 1) acc+bias -> LDS bf16 [256][256], 16B-chunk XOR swizzle:
    //    phys short idx = row*256 + (col ^ ((row&7)<<3))
#pragma unroll
    for (int j = 0; j < 4; j++) {
        const int colL = wave_n * 64 + j * 16 + cn;
        const float bv = bias[col0 + colL];
#pragma unroll
        for (int i = 0; i < 8; i++)
#pragma unroll
            for (int r = 0; r < 4; r++) {
                const int lr = wave_m * 128 + i * 16 + cq + r;
                smem[lr * 256 + (colL ^ ((lr & 7) << 3))] = f2bf(acc[i][j][r] + bv);
            }
    }
    __syncthreads();

    // 2) coalesced read-back: thread owns (row R = t>>1, half = t&1) = 128
    //    contiguous shorts = 2 complete heads; Q softmax applied in-thread.
    {
        unsigned short* outp = (bx < 4) ? Qo : ((bx < 8) ? Ko : Vo);
        const bool isQ = (bx < 4);
        const int R = t >> 1, half = t & 1;
        const size_t obase = (size_t)(row0 + R) * CC + (col0 & 1023) + half * 128;
        unsigned short* orow = &outp[obase];

#pragma unroll
        for (int g = 0; g < 2; g++) {           // two 64-short head groups
            short8 bufv[8];
            const int cbase = half * 16 + g * 8;
#pragma unroll
            for (int k = 0; k < 8; k++)
                bufv[k] = *reinterpret_cast<const short8*>(
                    &smem[R * 256 + (((cbase + k) ^ (R & 7)) << 3)]);
            if (isQ) {
                float v[64];
                float mx = -3.0e38f;
#pragma unroll
                for (int k = 0; k < 8; k++)
#pragma unroll
                    for (int e = 0; e < 8; e++) {
                        const float f = bf2f((unsigned short)bufv[k][e]);
                        v[k * 8 + e] = f;
                        mx = fmaxf(mx, f);
                    }
                float s = 0.0f;
#pragma unroll
                for (int q = 0; q < 64; q++) {
                    const float ev = __expf(v[q] - mx);
                    v[q] = ev;
                    s += ev;
                }
                const float inv = 1.0f / s;
#pragma unroll
                for (int k = 0; k < 8; k++)
#pragma unroll
                    for (int e = 0; e < 8; e++)
                        bufv[k][e] = (short)f2bf(v[k * 8 + e] * inv);
            }
#pragma unroll
            for (int k = 0; k < 8; k++)
                *reinterpret_cast<short8*>(&orow[g * 64 + k * 8]) = bufv[k];
        }
    }
}

// ---------------------------------------------------------------------------
// Single-pass K/V context: ctx_u[bh,d,e] += sum_n exp(K[n,d]) * V[n,e]
//                          csum[bh,d]   += sum_n exp(K[n,d])
// ---------------------------------------------------------------------------
__global__ __launch_bounds__(256) void kv_ctx_kernel(
    const unsigned short* __restrict__ Km, const unsigned short* __restrict__ Vm,
    float* __restrict__ ctx, float* __restrict__ csum)
{
    const int bh = blockIdx.x, ch = blockIdx.y;
    const int b = bh >> 4, h = bh & 15;
    const int t = threadIdx.x;

    __shared__ float Ks[32][68];
    __shared__ float Vs[32][68];
    __shared__ float cred[4][64];

    const int d0 = (t >> 4) * 4, e0 = (t & 15) * 4;
    float acc[4][4];
#pragma unroll
    for (int i = 0; i < 4; i++)
#pragma unroll
        for (int j = 0; j < 4; j++) acc[i][j] = 0.0f;
    float csacc = 0.0f;
    const int dc = t & 63, rq = (t >> 6) * 8;

    const size_t base = (size_t)(b * SEQ + ch * 256) * CC + (size_t)h * 64;

    for (int n0 = 0; n0 < 256; n0 += 32) {
        __syncthreads();
#pragma unroll
        for (int l = 0; l < 2; l++) {
            const int idx = t + l * 256;
            const int r = idx >> 4, c4 = (idx & 15) * 4;
            ushort4 kv = *reinterpret_cast<const ushort4*>(&Km[base + (size_t)(n0 + r) * CC + c4]);
            ushort4 vv = *reinterpret_cast<const ushort4*>(&Vm[base + (size_t)(n0 + r) * CC + c4]);
            float4 kf;
            kf.x = __expf(bf2f(kv.x));
            kf.y = __expf(bf2f(kv.y));
            kf.z = __expf(bf2f(kv.z));
            kf.w = __expf(bf2f(kv.w));
            float4 vf = {bf2f(vv.x), bf2f(vv.y), bf2f(vv.z), bf2f(vv.w)};
            *reinterpret_cast<float4*>(&Ks[r][c4]) = kf;
            *reinterpret_cast<float4*>(&Vs[r][c4]) = vf;
        }
        __syncthreads();

#pragma unroll
        for (int r = 0; r < 8; r++) csacc += Ks[rq + r][dc];

#pragma unroll 8
        for (int n = 0; n < 32; n++) {
            float4 a = *reinterpret_cast<const float4*>(&Ks[n][d0]);
            float4 v4 = *reinterpret_cast<const float4*>(&Vs[n][e0]);
            float a4[4] = {a.x, a.y, a.z, a.w};
            float b4[4] = {v4.x, v4.y, v4.z, v4.w};
#pragma unroll
            for (int i = 0; i < 4; i++)
#pragma unroll
                for (int j = 0; j < 4; j++)
                    acc[i][j] += a4[i] * b4[j];
        }
    }

    __syncthreads();
    cred[t >> 6][dc] = csacc;
    __syncthreads();
    if (t < 64)
        atomicAdd(&csum[(size_t)bh * 64 + t],
                  cred[0][t] + cred[1][t] + cred[2][t] + cred[3][t]);

#pragma unroll
    for (int i = 0; i < 4; i++)
#pragma unroll
        for (int j = 0; j < 4; j++)
            atomicAdd(&ctx[((size_t)bh * 64 + d0 + i) * 64 + e0 + j], acc[i][j]);
}

// ---------------------------------------------------------------------------
// W_eff build: WeffT[b][n][h*64+d] = f2bf( (1/csum[bh,d]) *
//                                     sum_e ctx_u[b,h,d,e] * Wp[h*64+e, n] )
// ---------------------------------------------------------------------------
__global__ __launch_bounds__(256) void weff_kernel(
    const float* __restrict__ ctx, const float* __restrict__ csum,
    const float* __restrict__ Wp, unsigned short* __restrict__ WeffT)
{
    const int bh = blockIdx.x, nc = blockIdx.y;
    const int b = bh >> 4, h = bh & 15;
    const int t = threadIdx.x;

    __shared__ float ctxs[64 * 64];
    __shared__ float cinvs[64];
#pragma unroll
    for (int l = 0; l < 16; l++)
        ctxs[t + l * 256] = ctx[(size_t)bh * 4096 + t + l * 256];
    if (t < 64) cinvs[t] = 1.0f / csum[(size_t)bh * 64 + t];
    __syncthreads();

    const int n = nc * 128 + (t & 127);
    const int dg = (t >> 7) * 32;

    float acc[32];
#pragma unroll
    for (int d = 0; d < 32; d++) acc[d] = 0.0f;

    for (int e = 0; e < 64; e++) {
        const float w = Wp[(size_t)(h * 64 + e) * CC + n];
#pragma unroll
        for (int d = 0; d < 32; d++)
            acc[d] += ctxs[(dg + d) * 64 + e] * w;
    }

    const size_t obase = ((size_t)b << 20) + (size_t)n * CC + h * 64 + dg;
#pragma unroll
    for (int d = 0; d < 32; d += 2) {
        ushort2 o;
        o.x = f2bf(acc[d] * cinvs[dg + d]);
        o.y = f2bf(acc[d + 1] * cinvs[dg + d + 1]);
        *reinterpret_cast<ushort2*>(&WeffT[obase + d]) = o;
    }
}

// ---------------------------------------------------------------------------
extern "C" void kernel_launch(void* const* d_in, const int* in_sizes, int n_in,
                              void* d_out, int out_size, void* d_ws, size_t ws_size,
                              hipStream_t stream)
{
    const float* x      = (const float*)d_in[0];
    const float* W_qkv  = (const float*)d_in[1];
    const float* b_qkv  = (const float*)d_in[2];
    const float* W_proj = (const float*)d_in[3];
    const float* b_proj = (const float*)d_in[4];
    float* out = (float*)d_out;

    unsigned short* Qm  = (unsigned short*)d_ws;               // [16384,1024] bf16
    unsigned short* Km  = Qm + (size_t)TOKENS * CC;
    unsigned short* Vm  = Km + (size_t)TOKENS * CC;
    unsigned short* xb  = Vm + (size_t)TOKENS * CC;            // x bf16
    unsigned short* wqT = xb + (size_t)TOKENS * CC;            // [3072,1024]
    unsigned short* WeffT = wqT + (size_t)QKV3 * CC;           // [4,1024,1024] bf16
    float* ctx  = (float*)(WeffT + (size_t)BBATCH * CC * CC);  // [64,64,64] fp32
    float* csum = ctx + (size_t)64 * 64 * 64;                  // [64,64]

    hipMemsetAsync(ctx, 0, ((size_t)64 * 64 * 64 + 64 * 64) * sizeof(float), stream);

    // 0) x -> bf16; W_qkv -> bf16 transposed
    cvt_bf16_kernel<<<(TOKENS * CC / 4 + 255) / 256, 256, 0, stream>>>(
        x, xb, (long)TOKENS * CC / 4);
    transpose_bf16_kernel<<<dim3(QKV3 / 32, CC / 32), 256, 0, stream>>>(
        W_qkv, CC, QKV3, wqT);

    // 1) QKV GEMM -> Q / K / V bf16 (256^2 8-phase, deep pipeline,
    //    fused Q softmax in coalesced LDS epilogue)
    gemm256_bf16_kernel<1><<<dim3(QKV3 / 256, TOKENS / 256), 512, 0, stream>>>(
        xb, CC, wqT, CC, b_qkv, (float*)nullptr, 0, Qm, Km, Vm);

    // 2) single-pass exp(K)/V -> ctx_u + csum
    kv_ctx_kernel<<<dim3(BBATCH * HH, 16), 256, 0, stream>>>(Km, Vm, ctx, csum);

    // 3) effective projection weights per batch (applies 1/csum)
    weff_kernel<<<dim3(BBATCH * HH, 8), 256, 0, stream>>>(ctx, csum, W_proj, WeffT);

    // 4) out = Qhat @ WeffT[batch] + b_proj (256^2 8-phase)
    gemm256_bf16_kernel<0><<<dim3(CC / 256, TOKENS / 256), 512, 0, stream>>>(
        Qm, CC, WeffT, CC, b_proj, out, CC, nullptr, nullptr, nullptr);
}

// Round 4
// 371.302 us; speedup vs baseline: 1.2284x; 1.1129x over previous
//
#include <hip/hip_runtime.h>

// Problem constants
#define BBATCH 4
#define SEQ 4096
#define CC 1024
#define HH 16
#define DD 64
#define TOKENS 16384              // B*N
#define QKV3 3072                 // 3*C

typedef __attribute__((ext_vector_type(8))) short short8;
typedef __attribute__((ext_vector_type(4))) float floatx4;

// bf16 helpers (RNE)
__device__ __forceinline__ unsigned short f2bf(float x) {
    unsigned int u = __float_as_uint(x);
    u += 0x7fff + ((u >> 16) & 1);
    return (unsigned short)(u >> 16);
}
__device__ __forceinline__ float bf2f(unsigned short h) {
    return __uint_as_float((unsigned int)h << 16);
}

__device__ __forceinline__ void gload_lds16(const void* g, void* l) {
    __builtin_amdgcn_global_load_lds(
        (const __attribute__((address_space(1))) unsigned int*)g,
        (__attribute__((address_space(3))) unsigned int*)l, 16, 0, 0);
}

// ---------------------------------------------------------------------------
// fp32 -> bf16 convert (x)
// ---------------------------------------------------------------------------
__global__ __launch_bounds__(256) void cvt_bf16_kernel(
    const float* __restrict__ X, unsigned short* __restrict__ Y, long n4)
{
    long i = (long)blockIdx.x * 256 + threadIdx.x;
    if (i >= n4) return;
    float4 v = *reinterpret_cast<const float4*>(&X[i * 4]);
    ushort4 h;
    h.x = f2bf(v.x); h.y = f2bf(v.y); h.z = f2bf(v.z); h.w = f2bf(v.w);
    *reinterpret_cast<ushort4*>(&Y[i * 4]) = h;
}

// ---------------------------------------------------------------------------
// Transpose W[K,N] -> T[N,K] bf16. 32x32 tiles, 256 threads.
// ---------------------------------------------------------------------------
__global__ __launch_bounds__(256) void transpose_bf16_kernel(
    const float* __restrict__ W, int K, int N, unsigned short* __restrict__ T)
{
    __shared__ unsigned short Lh[32][36];
    const int k0 = blockIdx.y * 32, n0 = blockIdx.x * 32;
    const int t = threadIdx.x;
    const int r = t >> 3, c4 = (t & 7) * 4;

    float4 w = *reinterpret_cast<const float4*>(&W[(size_t)(k0 + r) * N + n0 + c4]);
    Lh[r][c4 + 0] = f2bf(w.x);
    Lh[r][c4 + 1] = f2bf(w.y);
    Lh[r][c4 + 2] = f2bf(w.z);
    Lh[r][c4 + 3] = f2bf(w.w);
    __syncthreads();

    const int rn = t >> 3, ck = (t & 7) * 4;
    ushort4 h4;
    h4.x = Lh[ck + 0][rn]; h4.y = Lh[ck + 1][rn];
    h4.z = Lh[ck + 2][rn]; h4.w = Lh[ck + 3][rn];
    *reinterpret_cast<ushort4*>(&T[(size_t)(n0 + rn) * K + k0 + ck]) = h4;
}

// ---------------------------------------------------------------------------
// 256x256 8-phase bf16 GEMM (HK-style template, plain HIP).
//   BM=BN=256, BK=64, 512 threads = 8 waves (2M x 4N), per-wave 128x64 out.
//   LDS 128 KiB: 2 dbuf x (A 256x64 + B 256x64) bf16, XOR-swizzled rows
//   (inverse swizzle applied on the per-lane GLOBAL source of gload_lds).
//   Schedule: R1 variant (measured best, MfmaUtil 32.2): KTILE(t) computes
//   from CUR, stages parts 1-3 of tile TN into OTH during P1-P3, part 0 of
//   TX into CUR at P4, vmcnt(2) once per K-tile.
//   T5: setprio around MFMA clusters. T1: XCD-bijective blockIdx swizzle.
// MODE 0: out GEMM (per-batch WeffT, fp32 direct store + bias).
// MODE 1: QKV GEMM. Epilogue: acc+bias -> LDS (256x256 bf16 = 128KiB,
//         16B-chunk XOR swizzle), coalesced ushort8 read-back + store;
//         read-back thread holds 2 complete heads -> Q softmax fused here.
// K fixed at 1024 -> 16 K-tiles.
// ---------------------------------------------------------------------------
template <int MODE>
__global__ __launch_bounds__(512) void gemm256_bf16_kernel(
    const unsigned short* __restrict__ A, int lda,
    const unsigned short* __restrict__ Bt, int ldb,
    const float* __restrict__ bias,
    float* __restrict__ Cf, int ldc,
    unsigned short* __restrict__ Qo, unsigned short* __restrict__ Ko,
    unsigned short* __restrict__ Vo)
{
    // buf0: A @ [0,16384), B @ [16384,32768); buf1: +32768   (shorts)
    __shared__ unsigned short smem[65536];   // 128 KiB

    const int t = threadIdx.x;
    const int wave = t >> 6, lane = t & 63;

    // T1: XCD-bijective swizzle (nwg % 8 == 0 for both grids)
    const int gx = gridDim.x;
    const int nwg = gx * gridDim.y;
    const int id0 = blockIdx.y * gx + blockIdx.x;
    const int cpx = nwg >> 3;
    const int swzid = (id0 & 7) * cpx + (id0 >> 3);
    const int bx = swzid % gx, by = swzid / gx;

    const int row0 = by * 256, col0 = bx * 256;
    const int wave_m = wave >> 2, wave_n = wave & 3;

    const unsigned short* Bp = Bt;
    if (MODE == 0) Bp += ((size_t)(row0 >> 12)) << 20;   // per-batch WeffT

    // fragment-read lane constants (swizzled LDS addressing, in shorts)
    const int fr  = lane & 15;
    const int fqb = (lane >> 4) << 4;                 // 16B chunk byte-offset
    const int sm  = (fr & 7) << 4;
    const int ck0 = ((0  + fqb) ^ sm) >> 1;           // k-slice 0 col (shorts)
    const int ck1 = ((64 + fqb) ^ sm) >> 1;           // k-slice 1 col (shorts)
    const int aRow = (wave_m * 128 + fr) * 64;        // within A region
    const int bRow = (wave_n * 64 + fr) * 64;         // within B region

    // staging lane constants: linear LDS dest, inverse-swizzled global source
    int srow[2], scol[2];
#pragma unroll
    for (int e = 0; e < 2; e++) {
        const int P  = (wave << 10) + (lane << 4) + (e << 13);  // byte in half
        const int r  = P >> 7;
        const int pc = P & 127;
        srow[e] = r;
        scol[e] = (pc ^ ((r & 7) << 4)) >> 1;         // bf16 col within 64
    }

    // stage one 128x64 half-tile: part = isB*2 + half
    auto STAGE_PART = [&](int kt, int buf, int part) {
        const int isB = part >> 1, half = part & 1;
        const unsigned short* p = isB ? Bp : A;
        const int r0 = isB ? col0 : row0;
        const int ld = isB ? ldb : lda;
        const int ldsOff = buf * 32768 + isB * 16384 + half * 8192 + wave * 512;
#pragma unroll
        for (int e = 0; e < 2; e++)
            gload_lds16(&p[(size_t)(r0 + half * 128 + srow[e]) * ld
                           + ((kt & 15) << 6) + scol[e]],
                        &smem[ldsOff + e * 4096]);
    };

    floatx4 acc[8][4];
#pragma unroll
    for (int i = 0; i < 8; i++)
#pragma unroll
        for (int j = 0; j < 4; j++) acc[i][j] = (floatx4)0.0f;

    short8 a[4][2], bl[2][2], bh[2][2];

#define RDA(BUF, IH)                                                          \
    _Pragma("unroll") for (int ii = 0; ii < 4; ii++) {                        \
        a[ii][0] = *reinterpret_cast<const short8*>(                          \
            &smem[(BUF) * 32768 + aRow + ((IH) * 64 + ii * 16) * 64 + ck0]);  \
        a[ii][1] = *reinterpret_cast<const short8*>(                          \
            &smem[(BUF) * 32768 + aRow + ((IH) * 64 + ii * 16) * 64 + ck1]);  \
    }
#define RDB(BUF, JH, DST)                                                     \
    _Pragma("unroll") for (int jj = 0; jj < 2; jj++) {                        \
        DST[jj][0] = *reinterpret_cast<const short8*>(                        \
            &smem[(BUF) * 32768 + 16384 + bRow + ((JH) * 32 + jj * 16) * 64 + ck0]); \
        DST[jj][1] = *reinterpret_cast<const short8*>(                        \
            &smem[(BUF) * 32768 + 16384 + bRow + ((JH) * 32 + jj * 16) * 64 + ck1]); \
    }
#define MFMA_Q(IH, JH, BB)                                                    \
    __builtin_amdgcn_s_setprio(1);                                            \
    _Pragma("unroll") for (int ii = 0; ii < 4; ii++)                          \
    _Pragma("unroll") for (int jj = 0; jj < 2; jj++) {                        \
        acc[(IH)*4+ii][(JH)*2+jj] = __builtin_amdgcn_mfma_f32_16x16x32_bf16(  \
            a[ii][0], BB[jj][0], acc[(IH)*4+ii][(JH)*2+jj], 0, 0, 0);         \
        acc[(IH)*4+ii][(JH)*2+jj] = __builtin_amdgcn_mfma_f32_16x16x32_bf16(  \
            a[ii][1], BB[jj][1], acc[(IH)*4+ii][(JH)*2+jj], 0, 0, 0);         \
    }                                                                         \
    __builtin_amdgcn_s_setprio(0);
#define BARRIER __builtin_amdgcn_s_barrier()
#define WAIT_LGKM asm volatile("s_waitcnt lgkmcnt(0)" ::: "memory")
#define WAIT_VM2  asm volatile("s_waitcnt vmcnt(2)" ::: "memory")

    // R1 schedule: P1-P3 finish tile TN into OTH, P4 starts TX into CUR
    // (CUR's LDS fully read by end of P3).
#define KTILE(CUR, OTH, TN, TX)                                               \
    {                                                                         \
        RDA(CUR, 0); RDB(CUR, 0, bl);                                         \
        STAGE_PART(TN, OTH, 1);                                               \
        BARRIER; WAIT_LGKM; MFMA_Q(0, 0, bl); BARRIER;                        \
        RDB(CUR, 1, bh);                                                      \
        STAGE_PART(TN, OTH, 2);                                               \
        BARRIER; WAIT_LGKM; MFMA_Q(0, 1, bh); BARRIER;                        \
        RDA(CUR, 1);                                                          \
        STAGE_PART(TN, OTH, 3);                                               \
        BARRIER; WAIT_LGKM; MFMA_Q(1, 1, bh); BARRIER;                        \
        STAGE_PART(TX, CUR, 0);                                               \
        WAIT_VM2;                                                             \
        BARRIER;                                                              \
        MFMA_Q(1, 0, bl);                                                     \
        BARRIER;                                                              \
    }

    // prologue: tile0 fully staged + tile1 part0; wait tile0 (2 in flight)
    STAGE_PART(0, 0, 0); STAGE_PART(0, 0, 1);
    STAGE_PART(0, 0, 2); STAGE_PART(0, 0, 3);
    STAGE_PART(1, 1, 0);
    WAIT_VM2;
    BARRIER;

#pragma unroll 1
    for (int it = 0; it < 8; it++) {
        const int t1 = 2 * it + 1, t2 = 2 * it + 2, t3 = 2 * it + 3;
        KTILE(0, 1, t1, t2);      // compute K-tile 2*it   (buf0)
        KTILE(1, 0, t2, t3);      // compute K-tile 2*it+1 (buf1)
    }

#undef KTILE
#undef WAIT_VM2
#undef WAIT_LGKM
#undef BARRIER
#undef MFMA_Q
#undef RDB
#undef RDA

    // ---- epilogue ----
    // C/D layout: col = lane&15, row = (lane>>4)*4 + reg [m89]
    const int cn = lane & 15, cq = (lane >> 4) * 4;

    if (MODE == 0) {
        // fp32 direct store: 16 lanes cover a full 64B line -> no amplification
#pragma unroll
        for (int j = 0; j < 4; j++) {
            const int col = col0 + wave_n * 64 + j * 16 + cn;
            const float bv = bias[col];
#pragma unroll
            for (int i = 0; i < 8; i++)
#pragma unroll
                for (int r = 0; r < 4; r++) {
                    const int row = row0 + wave_m * 128 + i * 16 + cq + r;
                    Cf[(size_t)row * ldc + col] = acc[i][j][r] + bv;
                }
        }
        return;
    }

    // MODE 1: LDS-staged coalesced epilogue with fused Q softmax.
    // Drain in-flight gload_lds (wrapped tail prefetch) before reusing smem.
    __syncthreads();   // emits s_waitcnt vmcnt(0) lgkmcnt(0) + s_barrier

    // 1) acc+bias -> LDS bf16 [256][256], 16B-chunk XOR swizzle:
    //    phys short idx = row*256 + (col ^ ((row&7)<<3))
#pragma unroll
    for (int j = 0; j < 4; j++) {
        const int colL = wave_n * 64 + j * 16 + cn;
        const float bv = bias[col0 + colL];
#pragma unroll
        for (int i = 0; i < 8; i++)
#pragma unroll
            for (int r = 0; r < 4; r++) {
                const int lr = wave_m * 128 + i * 16 + cq + r;
                smem[lr * 256 + (colL ^ ((lr & 7) << 3))] = f2bf(acc[i][j][r] + bv);
            }
    }
    __syncthreads();

    // 2) coalesced read-back: thread owns (row R = t>>1, half = t&1) = 128
    //    contiguous shorts = 2 complete heads; Q softmax applied in-thread.
    {
        unsigned short* outp = (bx < 4) ? Qo : ((bx < 8) ? Ko : Vo);
        const bool isQ = (bx < 4);
        const int R = t >> 1, half = t & 1;
        const size_t obase = (size_t)(row0 + R) * CC + (col0 & 1023) + half * 128;
        unsigned short* orow = &outp[obase];

#pragma unroll
        for (int g = 0; g < 2; g++) {           // two 64-short head groups
            short8 bufv[8];
            const int cbase = half * 16 + g * 8;
#pragma unroll
            for (int k = 0; k < 8; k++)
                bufv[k] = *reinterpret_cast<const short8*>(
                    &smem[R * 256 + (((cbase + k) ^ (R & 7)) << 3)]);
            if (isQ) {
                float v[64];
                float mx = -3.0e38f;
#pragma unroll
                for (int k = 0; k < 8; k++)
#pragma unroll
                    for (int e = 0; e < 8; e++) {
                        const float f = bf2f((unsigned short)bufv[k][e]);
                        v[k * 8 + e] = f;
                        mx = fmaxf(mx, f);
                    }
                float s = 0.0f;
#pragma unroll
                for (int q = 0; q < 64; q++) {
                    const float ev = __expf(v[q] - mx);
                    v[q] = ev;
                    s += ev;
                }
                const float inv = 1.0f / s;
#pragma unroll
                for (int k = 0; k < 8; k++)
#pragma unroll
                    for (int e = 0; e < 8; e++)
                        bufv[k][e] = (short)f2bf(v[k * 8 + e] * inv);
            }
#pragma unroll
            for (int k = 0; k < 8; k++)
                *reinterpret_cast<short8*>(&orow[g * 64 + k * 8]) = bufv[k];
        }
    }
}

// ---------------------------------------------------------------------------
// Single-pass K/V context, ATOMIC-FREE: each (bh, ch) block writes its
// private partial: ctx_p[ch][bh][64*64], csum_p[ch][bh][64]. Plain coalesced
// float4 stores (prev: 4.19M contended device-scope atomicAdds).
// ---------------------------------------------------------------------------
__global__ __launch_bounds__(256) void kv_ctx_kernel(
    const unsigned short* __restrict__ Km, const unsigned short* __restrict__ Vm,
    float* __restrict__ ctx_p, float* __restrict__ csum_p)
{
    const int bh = blockIdx.x, ch = blockIdx.y;
    const int b = bh >> 4, h = bh & 15;
    const int t = threadIdx.x;

    __shared__ float Ks[32][68];
    __shared__ float Vs[32][68];
    __shared__ float cred[4][64];

    const int d0 = (t >> 4) * 4, e0 = (t & 15) * 4;
    float acc[4][4];
#pragma unroll
    for (int i = 0; i < 4; i++)
#pragma unroll
        for (int j = 0; j < 4; j++) acc[i][j] = 0.0f;
    float csacc = 0.0f;
    const int dc = t & 63, rq = (t >> 6) * 8;

    const size_t base = (size_t)(b * SEQ + ch * 256) * CC + (size_t)h * 64;

    for (int n0 = 0; n0 < 256; n0 += 32) {
        __syncthreads();
#pragma unroll
        for (int l = 0; l < 2; l++) {
            const int idx = t + l * 256;
            const int r = idx >> 4, c4 = (idx & 15) * 4;
            ushort4 kv = *reinterpret_cast<const ushort4*>(&Km[base + (size_t)(n0 + r) * CC + c4]);
            ushort4 vv = *reinterpret_cast<const ushort4*>(&Vm[base + (size_t)(n0 + r) * CC + c4]);
            float4 kf;
            kf.x = __expf(bf2f(kv.x));
            kf.y = __expf(bf2f(kv.y));
            kf.z = __expf(bf2f(kv.z));
            kf.w = __expf(bf2f(kv.w));
            float4 vf = {bf2f(vv.x), bf2f(vv.y), bf2f(vv.z), bf2f(vv.w)};
            *reinterpret_cast<float4*>(&Ks[r][c4]) = kf;
            *reinterpret_cast<float4*>(&Vs[r][c4]) = vf;
        }
        __syncthreads();

#pragma unroll
        for (int r = 0; r < 8; r++) csacc += Ks[rq + r][dc];

#pragma unroll 8
        for (int n = 0; n < 32; n++) {
            float4 a = *reinterpret_cast<const float4*>(&Ks[n][d0]);
            float4 v4 = *reinterpret_cast<const float4*>(&Vs[n][e0]);
            float a4[4] = {a.x, a.y, a.z, a.w};
            float b4[4] = {v4.x, v4.y, v4.z, v4.w};
#pragma unroll
            for (int i = 0; i < 4; i++)
#pragma unroll
                for (int j = 0; j < 4; j++)
                    acc[i][j] += a4[i] * b4[j];
        }
    }

    __syncthreads();
    cred[t >> 6][dc] = csacc;
    __syncthreads();

    const size_t pslot = (size_t)ch * 64 + bh;
    if (t < 64)
        csum_p[pslot * 64 + t] =
            cred[0][t] + cred[1][t] + cred[2][t] + cred[3][t];

    float* cp = &ctx_p[pslot * 4096];
#pragma unroll
    for (int i = 0; i < 4; i++) {
        float4 v4 = {acc[i][0], acc[i][1], acc[i][2], acc[i][3]};
        *reinterpret_cast<float4*>(&cp[(d0 + i) * 64 + e0]) = v4;
    }
}

// ---------------------------------------------------------------------------
// Reduce the 16 chunk-partials: ctx[bh][4096] = sum_p ctx_p[p][bh][4096],
// csum likewise. grid (64, 4), 256 thr; ~16 MB read total.
// ---------------------------------------------------------------------------
__global__ __launch_bounds__(256) void reduce_ctx_kernel(
    const float* __restrict__ ctx_p, const float* __restrict__ csum_p,
    float* __restrict__ ctx, float* __restrict__ csum)
{
    const int bh = blockIdx.x, q = blockIdx.y;
    const int t = threadIdx.x;
#pragma unroll
    for (int e = 0; e < 4; e++) {
        const int idx = (q * 4 + e) * 256 + t;
        float s = 0.0f;
#pragma unroll
        for (int p = 0; p < 16; p++)
            s += ctx_p[((size_t)p * 64 + bh) * 4096 + idx];
        ctx[(size_t)bh * 4096 + idx] = s;
    }
    if (q == 0 && t < 64) {
        float s = 0.0f;
#pragma unroll
        for (int p = 0; p < 16; p++)
            s += csum_p[((size_t)p * 64 + bh) * 64 + t];
        csum[(size_t)bh * 64 + t] = s;
    }
}

// ---------------------------------------------------------------------------
// W_eff build: WeffT[b][n][h*64+d] = f2bf( (1/csum[bh,d]) *
//                                     sum_e ctx_u[b,h,d,e] * Wp[h*64+e, n] )
// ---------------------------------------------------------------------------
__global__ __launch_bounds__(256) void weff_kernel(
    const float* __restrict__ ctx, const float* __restrict__ csum,
    const float* __restrict__ Wp, unsigned short* __restrict__ WeffT)
{
    const int bh = blockIdx.x, nc = blockIdx.y;
    const int b = bh >> 4, h = bh & 15;
    const int t = threadIdx.x;

    __shared__ float ctxs[64 * 64];
    __shared__ float cinvs[64];
#pragma unroll
    for (int l = 0; l < 16; l++)
        ctxs[t + l * 256] = ctx[(size_t)bh * 4096 + t + l * 256];
    if (t < 64) cinvs[t] = 1.0f / csum[(size_t)bh * 64 + t];
    __syncthreads();

    const int n = nc * 128 + (t & 127);
    const int dg = (t >> 7) * 32;

    float acc[32];
#pragma unroll
    for (int d = 0; d < 32; d++) acc[d] = 0.0f;

    for (int e = 0; e < 64; e++) {
        const float w = Wp[(size_t)(h * 64 + e) * CC + n];
#pragma unroll
        for (int d = 0; d < 32; d++)
            acc[d] += ctxs[(dg + d) * 64 + e] * w;
    }

    const size_t obase = ((size_t)b << 20) + (size_t)n * CC + h * 64 + dg;
#pragma unroll
    for (int d = 0; d < 32; d += 2) {
        ushort2 o;
        o.x = f2bf(acc[d] * cinvs[dg + d]);
        o.y = f2bf(acc[d + 1] * cinvs[dg + d + 1]);
        *reinterpret_cast<ushort2*>(&WeffT[obase + d]) = o;
    }
}

// ---------------------------------------------------------------------------
extern "C" void kernel_launch(void* const* d_in, const int* in_sizes, int n_in,
                              void* d_out, int out_size, void* d_ws, size_t ws_size,
                              hipStream_t stream)
{
    const float* x      = (const float*)d_in[0];
    const float* W_qkv  = (const float*)d_in[1];
    const float* b_qkv  = (const float*)d_in[2];
    const float* W_proj = (const float*)d_in[3];
    const float* b_proj = (const float*)d_in[4];
    float* out = (float*)d_out;

    // Workspace layout — identical footprint to the R2-passing run (~150 MB).
    // ctx_p/csum_p (17 MB) ALIAS xb (33.5 MB): xb is dead after the QKV GEMM
    // (dispatch 1); partials live only across dispatches 2-3. Stream-ordered.
    unsigned short* Qm  = (unsigned short*)d_ws;               // [16384,1024] bf16
    unsigned short* Km  = Qm + (size_t)TOKENS * CC;
    unsigned short* Vm  = Km + (size_t)TOKENS * CC;
    unsigned short* xb  = Vm + (size_t)TOKENS * CC;            // x bf16 (dead after QKV)
    unsigned short* wqT = xb + (size_t)TOKENS * CC;            // [3072,1024]
    unsigned short* WeffT = wqT + (size_t)QKV3 * CC;           // [4,1024,1024] bf16
    float* ctx    = (float*)(WeffT + (size_t)BBATCH * CC * CC);// [64,4096] fp32
    float* csum   = ctx + (size_t)64 * 4096;                   // [64,64]
    float* ctx_p  = (float*)xb;                                // [16,64,4096] (aliases xb)
    float* csum_p = ctx_p + (size_t)16 * 64 * 4096;            // [16,64,64]   (still in xb)

    // 0) x -> bf16; W_qkv -> bf16 transposed
    cvt_bf16_kernel<<<(TOKENS * CC / 4 + 255) / 256, 256, 0, stream>>>(
        x, xb, (long)TOKENS * CC / 4);
    transpose_bf16_kernel<<<dim3(QKV3 / 32, CC / 32), 256, 0, stream>>>(
        W_qkv, CC, QKV3, wqT);

    // 1) QKV GEMM -> Q / K / V bf16 (256^2 8-phase, fused Q softmax epilogue)
    gemm256_bf16_kernel<1><<<dim3(QKV3 / 256, TOKENS / 256), 512, 0, stream>>>(
        xb, CC, wqT, CC, b_qkv, (float*)nullptr, 0, Qm, Km, Vm);

    // 2) single-pass exp(K)/V -> per-chunk partials (no atomics)
    kv_ctx_kernel<<<dim3(BBATCH * HH, 16), 256, 0, stream>>>(Km, Vm, ctx_p, csum_p);

    // 3) reduce partials -> ctx, csum
    reduce_ctx_kernel<<<dim3(BBATCH * HH, 4), 256, 0, stream>>>(
        ctx_p, csum_p, ctx, csum);

    // 4) effective projection weights per batch (applies 1/csum)
    weff_kernel<<<dim3(BBATCH * HH, 8), 256, 0, stream>>>(ctx, csum, W_proj, WeffT);

    // 5) out = Qhat @ WeffT[batch] + b_proj (256^2 8-phase)
    gemm256_bf16_kernel<0><<<dim3(CC / 256, TOKENS / 256), 512, 0, stream>>>(
        Qm, CC, WeffT, CC, b_proj, out, CC, nullptr, nullptr, nullptr);
}

// Round 5
// 364.615 us; speedup vs baseline: 1.2510x; 1.0183x over previous
//
#include <hip/hip_runtime.h>

// Problem constants
#define BBATCH 4
#define SEQ 4096
#define CC 1024
#define HH 16
#define DD 64
#define TOKENS 16384              // B*N
#define QKV3 3072                 // 3*C

typedef __attribute__((ext_vector_type(8))) short short8;
typedef __attribute__((ext_vector_type(4))) float floatx4;

// bf16 helpers (RNE)
__device__ __forceinline__ unsigned short f2bf(float x) {
    unsigned int u = __float_as_uint(x);
    u += 0x7fff + ((u >> 16) & 1);
    return (unsigned short)(u >> 16);
}
__device__ __forceinline__ float bf2f(unsigned short h) {
    return __uint_as_float((unsigned int)h << 16);
}

__device__ __forceinline__ void gload_lds16(const void* g, void* l) {
    __builtin_amdgcn_global_load_lds(
        (const __attribute__((address_space(1))) unsigned int*)g,
        (__attribute__((address_space(3))) unsigned int*)l, 16, 0, 0);
}

// ---------------------------------------------------------------------------
// fp32 -> bf16 convert (x)
// ---------------------------------------------------------------------------
__global__ __launch_bounds__(256) void cvt_bf16_kernel(
    const float* __restrict__ X, unsigned short* __restrict__ Y, long n4)
{
    long i = (long)blockIdx.x * 256 + threadIdx.x;
    if (i >= n4) return;
    float4 v = *reinterpret_cast<const float4*>(&X[i * 4]);
    ushort4 h;
    h.x = f2bf(v.x); h.y = f2bf(v.y); h.z = f2bf(v.z); h.w = f2bf(v.w);
    *reinterpret_cast<ushort4*>(&Y[i * 4]) = h;
}

// ---------------------------------------------------------------------------
// Transpose W[K,N] -> T[N,K] bf16. 32x32 tiles, 256 threads.
// ---------------------------------------------------------------------------
__global__ __launch_bounds__(256) void transpose_bf16_kernel(
    const float* __restrict__ W, int K, int N, unsigned short* __restrict__ T)
{
    __shared__ unsigned short Lh[32][36];
    const int k0 = blockIdx.y * 32, n0 = blockIdx.x * 32;
    const int t = threadIdx.x;
    const int r = t >> 3, c4 = (t & 7) * 4;

    float4 w = *reinterpret_cast<const float4*>(&W[(size_t)(k0 + r) * N + n0 + c4]);
    Lh[r][c4 + 0] = f2bf(w.x);
    Lh[r][c4 + 1] = f2bf(w.y);
    Lh[r][c4 + 2] = f2bf(w.z);
    Lh[r][c4 + 3] = f2bf(w.w);
    __syncthreads();

    const int rn = t >> 3, ck = (t & 7) * 4;
    ushort4 h4;
    h4.x = Lh[ck + 0][rn]; h4.y = Lh[ck + 1][rn];
    h4.z = Lh[ck + 2][rn]; h4.w = Lh[ck + 3][rn];
    *reinterpret_cast<ushort4*>(&T[(size_t)(n0 + rn) * K + k0 + ck]) = h4;
}

// ---------------------------------------------------------------------------
// QKV GEMM: 256x256 8-phase bf16 (HK-style template, plain HIP). Unchanged
// from R4 (measured 134 us, MfmaUtil 32%, ~91% of the m248 K=1024 reference).
// Epilogue: acc+bias -> LDS (swizzled), coalesced ushort8 store, Q softmax
// fused in-thread.
// ---------------------------------------------------------------------------
__global__ __launch_bounds__(512) void gemm_qkv_kernel(
    const unsigned short* __restrict__ A, int lda,
    const unsigned short* __restrict__ Bt, int ldb,
    const float* __restrict__ bias,
    unsigned short* __restrict__ Qo, unsigned short* __restrict__ Ko,
    unsigned short* __restrict__ Vo)
{
    __shared__ unsigned short smem[65536];   // 128 KiB

    const int t = threadIdx.x;
    const int wave = t >> 6, lane = t & 63;

    const int gx = gridDim.x;
    const int nwg = gx * gridDim.y;
    const int id0 = blockIdx.y * gx + blockIdx.x;
    const int cpx = nwg >> 3;
    const int swzid = (id0 & 7) * cpx + (id0 >> 3);
    const int bx = swzid % gx, by = swzid / gx;

    const int row0 = by * 256, col0 = bx * 256;
    const int wave_m = wave >> 2, wave_n = wave & 3;

    const unsigned short* Bp = Bt;

    const int fr  = lane & 15;
    const int fqb = (lane >> 4) << 4;
    const int sm  = (fr & 7) << 4;
    const int ck0 = ((0  + fqb) ^ sm) >> 1;
    const int ck1 = ((64 + fqb) ^ sm) >> 1;
    const int aRow = (wave_m * 128 + fr) * 64;
    const int bRow = (wave_n * 64 + fr) * 64;

    int srow[2], scol[2];
#pragma unroll
    for (int e = 0; e < 2; e++) {
        const int P  = (wave << 10) + (lane << 4) + (e << 13);
        const int r  = P >> 7;
        const int pc = P & 127;
        srow[e] = r;
        scol[e] = (pc ^ ((r & 7) << 4)) >> 1;
    }

    auto STAGE_PART = [&](int kt, int buf, int part) {
        const int isB = part >> 1, half = part & 1;
        const unsigned short* p = isB ? Bp : A;
        const int r0 = isB ? col0 : row0;
        const int ld = isB ? ldb : lda;
        const int ldsOff = buf * 32768 + isB * 16384 + half * 8192 + wave * 512;
#pragma unroll
        for (int e = 0; e < 2; e++)
            gload_lds16(&p[(size_t)(r0 + half * 128 + srow[e]) * ld
                           + ((kt & 15) << 6) + scol[e]],
                        &smem[ldsOff + e * 4096]);
    };

    floatx4 acc[8][4];
#pragma unroll
    for (int i = 0; i < 8; i++)
#pragma unroll
        for (int j = 0; j < 4; j++) acc[i][j] = (floatx4)0.0f;

    short8 a[4][2], bl[2][2], bh[2][2];

#define RDA(BUF, IH)                                                          \
    _Pragma("unroll") for (int ii = 0; ii < 4; ii++) {                        \
        a[ii][0] = *reinterpret_cast<const short8*>(                          \
            &smem[(BUF) * 32768 + aRow + ((IH) * 64 + ii * 16) * 64 + ck0]);  \
        a[ii][1] = *reinterpret_cast<const short8*>(                          \
            &smem[(BUF) * 32768 + aRow + ((IH) * 64 + ii * 16) * 64 + ck1]);  \
    }
#define RDB(BUF, JH, DST)                                                     \
    _Pragma("unroll") for (int jj = 0; jj < 2; jj++) {                        \
        DST[jj][0] = *reinterpret_cast<const short8*>(                        \
            &smem[(BUF) * 32768 + 16384 + bRow + ((JH) * 32 + jj * 16) * 64 + ck0]); \
        DST[jj][1] = *reinterpret_cast<const short8*>(                        \
            &smem[(BUF) * 32768 + 16384 + bRow + ((JH) * 32 + jj * 16) * 64 + ck1]); \
    }
#define MFMA_Q(IH, JH, BB)                                                    \
    __builtin_amdgcn_s_setprio(1);                                            \
    _Pragma("unroll") for (int ii = 0; ii < 4; ii++)                          \
    _Pragma("unroll") for (int jj = 0; jj < 2; jj++) {                        \
        acc[(IH)*4+ii][(JH)*2+jj] = __builtin_amdgcn_mfma_f32_16x16x32_bf16(  \
            a[ii][0], BB[jj][0], acc[(IH)*4+ii][(JH)*2+jj], 0, 0, 0);         \
        acc[(IH)*4+ii][(JH)*2+jj] = __builtin_amdgcn_mfma_f32_16x16x32_bf16(  \
            a[ii][1], BB[jj][1], acc[(IH)*4+ii][(JH)*2+jj], 0, 0, 0);         \
    }                                                                         \
    __builtin_amdgcn_s_setprio(0);
#define BARRIER __builtin_amdgcn_s_barrier()
#define WAIT_LGKM asm volatile("s_waitcnt lgkmcnt(0)" ::: "memory")
#define WAIT_VM2  asm volatile("s_waitcnt vmcnt(2)" ::: "memory")

#define KTILE(CUR, OTH, TN, TX)                                               \
    {                                                                         \
        RDA(CUR, 0); RDB(CUR, 0, bl);                                         \
        STAGE_PART(TN, OTH, 1);                                               \
        BARRIER; WAIT_LGKM; MFMA_Q(0, 0, bl); BARRIER;                        \
        RDB(CUR, 1, bh);                                                      \
        STAGE_PART(TN, OTH, 2);                                               \
        BARRIER; WAIT_LGKM; MFMA_Q(0, 1, bh); BARRIER;                        \
        RDA(CUR, 1);                                                          \
        STAGE_PART(TN, OTH, 3);                                               \
        BARRIER; WAIT_LGKM; MFMA_Q(1, 1, bh); BARRIER;                        \
        STAGE_PART(TX, CUR, 0);                                               \
        WAIT_VM2;                                                             \
        BARRIER;                                                              \
        MFMA_Q(1, 0, bl);                                                     \
        BARRIER;                                                              \
    }

    STAGE_PART(0, 0, 0); STAGE_PART(0, 0, 1);
    STAGE_PART(0, 0, 2); STAGE_PART(0, 0, 3);
    STAGE_PART(1, 1, 0);
    WAIT_VM2;
    BARRIER;

#pragma unroll 1
    for (int it = 0; it < 8; it++) {
        const int t1 = 2 * it + 1, t2 = 2 * it + 2, t3 = 2 * it + 3;
        KTILE(0, 1, t1, t2);
        KTILE(1, 0, t2, t3);
    }

#undef KTILE
#undef WAIT_VM2
#undef WAIT_LGKM
#undef BARRIER
#undef MFMA_Q
#undef RDB
#undef RDA

    const int cn = lane & 15, cq = (lane >> 4) * 4;

    // LDS-staged coalesced epilogue with fused Q softmax.
    __syncthreads();   // drains vmcnt(0) lgkmcnt(0) + barrier

#pragma unroll
    for (int j = 0; j < 4; j++) {
        const int colL = wave_n * 64 + j * 16 + cn;
        const float bv = bias[col0 + colL];
#pragma unroll
        for (int i = 0; i < 8; i++)
#pragma unroll
            for (int r = 0; r < 4; r++) {
                const int lr = wave_m * 128 + i * 16 + cq + r;
                smem[lr * 256 + (colL ^ ((lr & 7) << 3))] = f2bf(acc[i][j][r] + bv);
            }
    }
    __syncthreads();

    {
        unsigned short* outp = (bx < 4) ? Qo : ((bx < 8) ? Ko : Vo);
        const bool isQ = (bx < 4);
        const int R = t >> 1, half = t & 1;
        const size_t obase = (size_t)(row0 + R) * CC + (col0 & 1023) + half * 128;
        unsigned short* orow = &outp[obase];

#pragma unroll
        for (int g = 0; g < 2; g++) {
            short8 bufv[8];
            const int cbase = half * 16 + g * 8;
#pragma unroll
            for (int k = 0; k < 8; k++)
                bufv[k] = *reinterpret_cast<const short8*>(
                    &smem[R * 256 + (((cbase + k) ^ (R & 7)) << 3)]);
            if (isQ) {
                float v[64];
                float mx = -3.0e38f;
#pragma unroll
                for (int k = 0; k < 8; k++)
#pragma unroll
                    for (int e = 0; e < 8; e++) {
                        const float f = bf2f((unsigned short)bufv[k][e]);
                        v[k * 8 + e] = f;
                        mx = fmaxf(mx, f);
                    }
                float s = 0.0f;
#pragma unroll
                for (int q = 0; q < 64; q++) {
                    const float ev = __expf(v[q] - mx);
                    v[q] = ev;
                    s += ev;
                }
                const float inv = 1.0f / s;
#pragma unroll
                for (int k = 0; k < 8; k++)
#pragma unroll
                    for (int e = 0; e < 8; e++)
                        bufv[k][e] = (short)f2bf(v[k * 8 + e] * inv);
            }
#pragma unroll
            for (int k = 0; k < 8; k++)
                *reinterpret_cast<short8*>(&orow[g * 64 + k * 8]) = bufv[k];
        }
    }
}

// ---------------------------------------------------------------------------
// Out GEMM (R5): 256x128 tile, BK=64, 512 thr = 8 waves (2M x 4N), per-wave
// 128x32 out, acc[8][2]. LDS 96 KiB (A 32K + B 16K per buf x 2). Grid 512
// blocks = 2 generations/CU -> gen-2 main loop overlaps gen-1 write drain.
// Schedule: 4 phases, vmcnt(2) once per K-tile (6 loads/tile: at the wait,
// outstanding = TN's 4 + TX's 2 -> drains TN exactly).
// B = per-batch WeffT (selected by row0>>12). fp32 store + bias.
// ---------------------------------------------------------------------------
__global__ __launch_bounds__(512) void gemm_out_kernel(
    const unsigned short* __restrict__ A, int lda,
    const unsigned short* __restrict__ Bt, int ldb,
    const float* __restrict__ bias,
    float* __restrict__ Cf, int ldc)
{
    // buf stride 24576 shorts: A @ +0 (16384), B @ +16384 (8192)
    __shared__ unsigned short smem[49152];   // 96 KiB

    const int t = threadIdx.x;
    const int wave = t >> 6, lane = t & 63;

    const int gx = gridDim.x;                 // 8
    const int nwg = gx * gridDim.y;           // 512
    const int id0 = blockIdx.y * gx + blockIdx.x;
    const int cpx = nwg >> 3;
    const int swzid = (id0 & 7) * cpx + (id0 >> 3);
    const int bx = swzid % gx, by = swzid / gx;

    const int row0 = by * 256, col0 = bx * 128;
    const int wave_m = wave >> 2, wave_n = wave & 3;

    const unsigned short* Bp = Bt + (((size_t)(row0 >> 12)) << 20);

    const int fr  = lane & 15;
    const int fqb = (lane >> 4) << 4;
    const int sm  = (fr & 7) << 4;
    const int ck0 = ((0  + fqb) ^ sm) >> 1;
    const int ck1 = ((64 + fqb) ^ sm) >> 1;
    const int aRow = (wave_m * 128 + fr) * 64;
    const int bRow = (wave_n * 32 + fr) * 64;

    int srow[2], scol[2];
#pragma unroll
    for (int e = 0; e < 2; e++) {
        const int P  = (wave << 10) + (lane << 4) + (e << 13);
        const int r  = P >> 7;
        const int pc = P & 127;
        srow[e] = r;
        scol[e] = (pc ^ ((r & 7) << 4)) >> 1;
    }

    // part: 0 = A half0, 1 = A half1, 2 = B (all 128 rows)
    auto STAGE_PART = [&](int kt, int buf, int part) {
        const int isB = (part == 2);
        const unsigned short* p = isB ? Bp : A;
        const int r0 = isB ? col0 : (row0 + (part & 1) * 128);
        const int ld = isB ? ldb : lda;
        const int ldsOff = buf * 24576 + (isB ? 16384 : (part & 1) * 8192) + wave * 512;
#pragma unroll
        for (int e = 0; e < 2; e++)
            gload_lds16(&p[(size_t)(r0 + srow[e]) * ld
                           + ((kt & 15) << 6) + scol[e]],
                        &smem[ldsOff + e * 4096]);
    };

    floatx4 acc[8][2];
#pragma unroll
    for (int i = 0; i < 8; i++)
#pragma unroll
        for (int j = 0; j < 2; j++) acc[i][j] = (floatx4)0.0f;

    short8 a[4][2], bb[2][2];

#define RDA(BUF, IH)                                                          \
    _Pragma("unroll") for (int ii = 0; ii < 4; ii++) {                        \
        a[ii][0] = *reinterpret_cast<const short8*>(                          \
            &smem[(BUF) * 24576 + aRow + ((IH) * 64 + ii * 16) * 64 + ck0]);  \
        a[ii][1] = *reinterpret_cast<const short8*>(                          \
            &smem[(BUF) * 24576 + aRow + ((IH) * 64 + ii * 16) * 64 + ck1]);  \
    }
#define RDB(BUF)                                                              \
    _Pragma("unroll") for (int jj = 0; jj < 2; jj++) {                        \
        bb[jj][0] = *reinterpret_cast<const short8*>(                         \
            &smem[(BUF) * 24576 + 16384 + bRow + (jj * 16) * 64 + ck0]);      \
        bb[jj][1] = *reinterpret_cast<const short8*>(                         \
            &smem[(BUF) * 24576 + 16384 + bRow + (jj * 16) * 64 + ck1]);      \
    }
#define MFMA_8(IH, J)                                                         \
    __builtin_amdgcn_s_setprio(1);                                            \
    _Pragma("unroll") for (int ii = 0; ii < 4; ii++) {                        \
        acc[(IH)*4+ii][(J)] = __builtin_amdgcn_mfma_f32_16x16x32_bf16(        \
            a[ii][0], bb[(J)][0], acc[(IH)*4+ii][(J)], 0, 0, 0);              \
        acc[(IH)*4+ii][(J)] = __builtin_amdgcn_mfma_f32_16x16x32_bf16(        \
            a[ii][1], bb[(J)][1], acc[(IH)*4+ii][(J)], 0, 0, 0);              \
    }                                                                         \
    __builtin_amdgcn_s_setprio(0);
#define BARRIER __builtin_amdgcn_s_barrier()
#define WAIT_LGKM asm volatile("s_waitcnt lgkmcnt(0)" ::: "memory")
#define WAIT_VM2  asm volatile("s_waitcnt vmcnt(2)" ::: "memory")

    // Per-K-tile loads: A half0/half1 + B = 6. At WAIT_VM2: outstanding =
    // TN{A1,B} (4) + TX{A0} (2) -> drains TN fully, leaves TX's 2.
#define KTILE(CUR, OTH, TN, TX)                                               \
    {                                                                         \
        RDA(CUR, 0); RDB(CUR);                                                \
        STAGE_PART(TN, OTH, 1);                                               \
        BARRIER; WAIT_LGKM; MFMA_8(0, 0); BARRIER;                            \
        STAGE_PART(TN, OTH, 2);                                               \
        BARRIER; MFMA_8(0, 1); BARRIER;                                       \
        RDA(CUR, 1);                                                          \
        BARRIER; WAIT_LGKM; MFMA_8(1, 1); BARRIER;                            \
        STAGE_PART(TX, CUR, 0);                                               \
        WAIT_VM2;                                                             \
        BARRIER;                                                              \
        MFMA_8(1, 0);                                                         \
        BARRIER;                                                              \
    }

    // prologue: tile0 {A0,A1,B} + tile1 {A0} = 8 loads; vmcnt(2) drains tile0
    STAGE_PART(0, 0, 0); STAGE_PART(0, 0, 1); STAGE_PART(0, 0, 2);
    STAGE_PART(1, 1, 0);
    WAIT_VM2;
    BARRIER;

#pragma unroll 1
    for (int it = 0; it < 8; it++) {
        const int t1 = 2 * it + 1, t2 = 2 * it + 2, t3 = 2 * it + 3;
        KTILE(0, 1, t1, t2);
        KTILE(1, 0, t2, t3);
    }

#undef KTILE
#undef WAIT_VM2
#undef WAIT_LGKM
#undef BARRIER
#undef MFMA_8
#undef RDB
#undef RDA

    // fp32 direct store: 16 lanes cover a full 64B segment
    const int cn = lane & 15, cq = (lane >> 4) * 4;
#pragma unroll
    for (int j = 0; j < 2; j++) {
        const int col = col0 + wave_n * 32 + j * 16 + cn;
        const float bv = bias[col];
#pragma unroll
        for (int i = 0; i < 8; i++)
#pragma unroll
            for (int r = 0; r < 4; r++) {
                const int row = row0 + wave_m * 128 + i * 16 + cq + r;
                Cf[(size_t)row * ldc + col] = acc[i][j][r] + bv;
            }
    }
}

// ---------------------------------------------------------------------------
// Single-pass K/V context, atomic-free, 16B loads (R5).
// ---------------------------------------------------------------------------
__global__ __launch_bounds__(256) void kv_ctx_kernel(
    const unsigned short* __restrict__ Km, const unsigned short* __restrict__ Vm,
    float* __restrict__ ctx_p, float* __restrict__ csum_p)
{
    const int bh = blockIdx.x, ch = blockIdx.y;
    const int b = bh >> 4, h = bh & 15;
    const int t = threadIdx.x;

    __shared__ float Ks[32][68];
    __shared__ float Vs[32][68];
    __shared__ float cred[4][64];

    const int d0 = (t >> 4) * 4, e0 = (t & 15) * 4;
    float acc[4][4];
#pragma unroll
    for (int i = 0; i < 4; i++)
#pragma unroll
        for (int j = 0; j < 4; j++) acc[i][j] = 0.0f;
    float csacc = 0.0f;
    const int dc = t & 63, rq = (t >> 6) * 8;

    const size_t base = (size_t)(b * SEQ + ch * 256) * CC + (size_t)h * 64;
    const int lr = t >> 3, lc = (t & 7) * 8;   // staging: 16 B/lane

    for (int n0 = 0; n0 < 256; n0 += 32) {
        __syncthreads();
        {
            short8 k8 = *reinterpret_cast<const short8*>(&Km[base + (size_t)(n0 + lr) * CC + lc]);
            short8 v8 = *reinterpret_cast<const short8*>(&Vm[base + (size_t)(n0 + lr) * CC + lc]);
            float4 ka, kb, va, vb;
            ka.x = __expf(bf2f((unsigned short)k8[0]));
            ka.y = __expf(bf2f((unsigned short)k8[1]));
            ka.z = __expf(bf2f((unsigned short)k8[2]));
            ka.w = __expf(bf2f((unsigned short)k8[3]));
            kb.x = __expf(bf2f((unsigned short)k8[4]));
            kb.y = __expf(bf2f((unsigned short)k8[5]));
            kb.z = __expf(bf2f((unsigned short)k8[6]));
            kb.w = __expf(bf2f((unsigned short)k8[7]));
            va.x = bf2f((unsigned short)v8[0]); va.y = bf2f((unsigned short)v8[1]);
            va.z = bf2f((unsigned short)v8[2]); va.w = bf2f((unsigned short)v8[3]);
            vb.x = bf2f((unsigned short)v8[4]); vb.y = bf2f((unsigned short)v8[5]);
            vb.z = bf2f((unsigned short)v8[6]); vb.w = bf2f((unsigned short)v8[7]);
            *reinterpret_cast<float4*>(&Ks[lr][lc])     = ka;
            *reinterpret_cast<float4*>(&Ks[lr][lc + 4]) = kb;
            *reinterpret_cast<float4*>(&Vs[lr][lc])     = va;
            *reinterpret_cast<float4*>(&Vs[lr][lc + 4]) = vb;
        }
        __syncthreads();

#pragma unroll
        for (int r = 0; r < 8; r++) csacc += Ks[rq + r][dc];

#pragma unroll 8
        for (int n = 0; n < 32; n++) {
            float4 a = *reinterpret_cast<const float4*>(&Ks[n][d0]);
            float4 v4 = *reinterpret_cast<const float4*>(&Vs[n][e0]);
            float a4[4] = {a.x, a.y, a.z, a.w};
            float b4[4] = {v4.x, v4.y, v4.z, v4.w};
#pragma unroll
            for (int i = 0; i < 4; i++)
#pragma unroll
                for (int j = 0; j < 4; j++)
                    acc[i][j] += a4[i] * b4[j];
        }
    }

    __syncthreads();
    cred[t >> 6][dc] = csacc;
    __syncthreads();

    const size_t pslot = (size_t)ch * 64 + bh;
    if (t < 64)
        csum_p[pslot * 64 + t] =
            cred[0][t] + cred[1][t] + cred[2][t] + cred[3][t];

    float* cp = &ctx_p[pslot * 4096];
#pragma unroll
    for (int i = 0; i < 4; i++) {
        float4 v4;
        v4.x = acc[i][0]; v4.y = acc[i][1]; v4.z = acc[i][2]; v4.w = acc[i][3];
        *reinterpret_cast<float4*>(&cp[(d0 + i) * 64 + e0]) = v4;
    }
}

// ---------------------------------------------------------------------------
// Reduce the 16 chunk-partials: ctx[bh][4096] = sum_p ctx_p[p][bh][4096].
// ---------------------------------------------------------------------------
__global__ __launch_bounds__(256) void reduce_ctx_kernel(
    const float* __restrict__ ctx_p, const float* __restrict__ csum_p,
    float* __restrict__ ctx, float* __restrict__ csum)
{
    const int bh = blockIdx.x, q = blockIdx.y;
    const int t = threadIdx.x;
#pragma unroll
    for (int e = 0; e < 4; e++) {
        const int idx = (q * 4 + e) * 256 + t;
        float s = 0.0f;
#pragma unroll
        for (int p = 0; p < 16; p++)
            s += ctx_p[((size_t)p * 64 + bh) * 4096 + idx];
        ctx[(size_t)bh * 4096 + idx] = s;
    }
    if (q == 0 && t < 64) {
        float s = 0.0f;
#pragma unroll
        for (int p = 0; p < 16; p++)
            s += csum_p[((size_t)p * 64 + bh) * 64 + t];
        csum[(size_t)bh * 64 + t] = s;
    }
}

// ---------------------------------------------------------------------------
// W_eff build (R5 rewrite): WeffT[b][n][h*64+d] = f2bf((1/csum[bh,d]) *
//     sum_e ctx[b,h,d,e] * Wp[h*64+e, n])
// Previous version: 2048 stride-64 scalar ds_read_b32 per thread (~40 us).
// Now: ctx staged TRANSPOSED [e][d] (pad 68) + Wp slice staged [e][128];
// thread owns 8d x 4n outer product -> per e: 3 ds_read_b128 + 32 fp32 FMA.
// grid (64 bh, 8 nc), 256 thr; LDS ~50 KiB.
// ---------------------------------------------------------------------------
__global__ __launch_bounds__(256) void weff_kernel(
    const float* __restrict__ ctx, const float* __restrict__ csum,
    const float* __restrict__ Wp, unsigned short* __restrict__ WeffT)
{
    const int bh = blockIdx.x, nc = blockIdx.y;
    const int b = bh >> 4, h = bh & 15;
    const int t = threadIdx.x;

    __shared__ float ctxsT[64 * 68];   // [e][d], pad 68 (16B-aligned rows)
    __shared__ float WpS[64 * 128];    // [e][n']
    __shared__ float cinvs[64];

#pragma unroll
    for (int l = 0; l < 16; l++) {
        const int idx = t + l * 256;            // idx = d*64 + e
        ctxsT[(idx & 63) * 68 + (idx >> 6)] = ctx[(size_t)bh * 4096 + idx];
    }
#pragma unroll
    for (int l = 0; l < 32; l++) {
        const int idx = t + l * 256;            // idx = e*128 + n'
        WpS[idx] = Wp[(size_t)(h * 64 + (idx >> 7)) * CC + nc * 128 + (idx & 127)];
    }
    if (t < 64) cinvs[t] = 1.0f / csum[(size_t)bh * 64 + t];
    __syncthreads();

    const int d0 = (t >> 5) * 8;     // 8 d-groups of 8
    const int n0 = (t & 31) * 4;     // 32 n-groups of 4

    float acc[8][4];
#pragma unroll
    for (int i = 0; i < 8; i++)
#pragma unroll
        for (int j = 0; j < 4; j++) acc[i][j] = 0.0f;

#pragma unroll 4
    for (int e = 0; e < 64; e++) {
        float4 c0 = *reinterpret_cast<const float4*>(&ctxsT[e * 68 + d0]);
        float4 c1 = *reinterpret_cast<const float4*>(&ctxsT[e * 68 + d0 + 4]);
        float4 w4 = *reinterpret_cast<const float4*>(&WpS[e * 128 + n0]);
        const float cc[8] = {c0.x, c0.y, c0.z, c0.w, c1.x, c1.y, c1.z, c1.w};
        const float ww[4] = {w4.x, w4.y, w4.z, w4.w};
#pragma unroll
        for (int i = 0; i < 8; i++)
#pragma unroll
            for (int j = 0; j < 4; j++)
                acc[i][j] += cc[i] * ww[j];
    }

    // store: 16 B (8 d's) per n, 4 n's per thread
    const size_t obase = ((size_t)b << 20) + (size_t)(nc * 128 + n0) * CC + h * 64 + d0;
#pragma unroll
    for (int j = 0; j < 4; j++) {
        short8 o;
#pragma unroll
        for (int i = 0; i < 8; i++)
            o[i] = (short)f2bf(acc[i][j] * cinvs[d0 + i]);
        *reinterpret_cast<short8*>(&WeffT[obase + (size_t)j * CC]) = o;
    }
}

// ---------------------------------------------------------------------------
extern "C" void kernel_launch(void* const* d_in, const int* in_sizes, int n_in,
                              void* d_out, int out_size, void* d_ws, size_t ws_size,
                              hipStream_t stream)
{
    const float* x      = (const float*)d_in[0];
    const float* W_qkv  = (const float*)d_in[1];
    const float* b_qkv  = (const float*)d_in[2];
    const float* W_proj = (const float*)d_in[3];
    const float* b_proj = (const float*)d_in[4];
    float* out = (float*)d_out;

    // Workspace layout — same footprint as the R2/R4-passing runs (~150 MB).
    // ctx_p/csum_p (17 MB) alias xb (33.5 MB): xb dead after QKV GEMM;
    // partials live only across dispatches 2-3. Stream-ordered.
    unsigned short* Qm  = (unsigned short*)d_ws;               // [16384,1024] bf16
    unsigned short* Km  = Qm + (size_t)TOKENS * CC;
    unsigned short* Vm  = Km + (size_t)TOKENS * CC;
    unsigned short* xb  = Vm + (size_t)TOKENS * CC;            // x bf16 (dead after QKV)
    unsigned short* wqT = xb + (size_t)TOKENS * CC;            // [3072,1024]
    unsigned short* WeffT = wqT + (size_t)QKV3 * CC;           // [4,1024,1024] bf16
    float* ctx    = (float*)(WeffT + (size_t)BBATCH * CC * CC);// [64,4096] fp32
    float* csum   = ctx + (size_t)64 * 4096;                   // [64,64]
    float* ctx_p  = (float*)xb;                                // [16,64,4096] (aliases xb)
    float* csum_p = ctx_p + (size_t)16 * 64 * 4096;            // [16,64,64]   (still in xb)

    // 0) x -> bf16; W_qkv -> bf16 transposed
    cvt_bf16_kernel<<<(TOKENS * CC / 4 + 255) / 256, 256, 0, stream>>>(
        x, xb, (long)TOKENS * CC / 4);
    transpose_bf16_kernel<<<dim3(QKV3 / 32, CC / 32), 256, 0, stream>>>(
        W_qkv, CC, QKV3, wqT);

    // 1) QKV GEMM -> Q / K / V bf16 (fused Q softmax epilogue)
    gemm_qkv_kernel<<<dim3(QKV3 / 256, TOKENS / 256), 512, 0, stream>>>(
        xb, CC, wqT, CC, b_qkv, Qm, Km, Vm);

    // 2) single-pass exp(K)/V -> per-chunk partials (no atomics)
    kv_ctx_kernel<<<dim3(BBATCH * HH, 16), 256, 0, stream>>>(Km, Vm, ctx_p, csum_p);

    // 3) reduce partials -> ctx, csum
    reduce_ctx_kernel<<<dim3(BBATCH * HH, 4), 256, 0, stream>>>(
        ctx_p, csum_p, ctx, csum);

    // 4) effective projection weights per batch (applies 1/csum)
    weff_kernel<<<dim3(BBATCH * HH, 8), 256, 0, stream>>>(ctx, csum, W_proj, WeffT);

    // 5) out = Qhat @ WeffT[batch] + b_proj (256x128 tile, 2 generations)
    gemm_out_kernel<<<dim3(CC / 128, TOKENS / 256), 512, 0, stream>>>(
        Qm, CC, WeffT, CC, b_proj, out, CC);
}

// Round 6
// 359.486 us; speedup vs baseline: 1.2688x; 1.0143x over previous
//
#include <hip/hip_runtime.h>

// Problem constants
#define BBATCH 4
#define SEQ 4096
#define CC 1024
#define HH 16
#define DD 64
#define TOKENS 16384              // B*N
#define QKV3 3072                 // 3*C

typedef __attribute__((ext_vector_type(8))) short short8;
typedef __attribute__((ext_vector_type(4))) float floatx4;

// bf16 helpers (RNE)
__device__ __forceinline__ unsigned short f2bf(float x) {
    unsigned int u = __float_as_uint(x);
    u += 0x7fff + ((u >> 16) & 1);
    return (unsigned short)(u >> 16);
}
__device__ __forceinline__ float bf2f(unsigned short h) {
    return __uint_as_float((unsigned int)h << 16);
}

__device__ __forceinline__ void gload_lds16(const void* g, void* l) {
    __builtin_amdgcn_global_load_lds(
        (const __attribute__((address_space(1))) unsigned int*)g,
        (__attribute__((address_space(3))) unsigned int*)l, 16, 0, 0);
}

// ---------------------------------------------------------------------------
// fp32 -> bf16 convert (x)
// ---------------------------------------------------------------------------
__global__ __launch_bounds__(256) void cvt_bf16_kernel(
    const float* __restrict__ X, unsigned short* __restrict__ Y, long n4)
{
    long i = (long)blockIdx.x * 256 + threadIdx.x;
    if (i >= n4) return;
    float4 v = *reinterpret_cast<const float4*>(&X[i * 4]);
    ushort4 h;
    h.x = f2bf(v.x); h.y = f2bf(v.y); h.z = f2bf(v.z); h.w = f2bf(v.w);
    *reinterpret_cast<ushort4*>(&Y[i * 4]) = h;
}

// ---------------------------------------------------------------------------
// Transpose W[K,N] -> T[N,K] bf16. 32x32 tiles, 256 threads.
// ---------------------------------------------------------------------------
__global__ __launch_bounds__(256) void transpose_bf16_kernel(
    const float* __restrict__ W, int K, int N, unsigned short* __restrict__ T)
{
    __shared__ unsigned short Lh[32][36];
    const int k0 = blockIdx.y * 32, n0 = blockIdx.x * 32;
    const int t = threadIdx.x;
    const int r = t >> 3, c4 = (t & 7) * 4;

    float4 w = *reinterpret_cast<const float4*>(&W[(size_t)(k0 + r) * N + n0 + c4]);
    Lh[r][c4 + 0] = f2bf(w.x);
    Lh[r][c4 + 1] = f2bf(w.y);
    Lh[r][c4 + 2] = f2bf(w.z);
    Lh[r][c4 + 3] = f2bf(w.w);
    __syncthreads();

    const int rn = t >> 3, ck = (t & 7) * 4;
    ushort4 h4;
    h4.x = Lh[ck + 0][rn]; h4.y = Lh[ck + 1][rn];
    h4.z = Lh[ck + 2][rn]; h4.w = Lh[ck + 3][rn];
    *reinterpret_cast<ushort4*>(&T[(size_t)(n0 + rn) * K + k0 + ck]) = h4;
}

// ---------------------------------------------------------------------------
// QKV GEMM: 256x256 8-phase bf16 (unchanged from R4/R5: 134 us, MfmaUtil 32%).
// Epilogue: acc+bias -> swizzled LDS, coalesced ushort8 store, fused Q softmax.
// ---------------------------------------------------------------------------
__global__ __launch_bounds__(512) void gemm_qkv_kernel(
    const unsigned short* __restrict__ A, int lda,
    const unsigned short* __restrict__ Bt, int ldb,
    const float* __restrict__ bias,
    unsigned short* __restrict__ Qo, unsigned short* __restrict__ Ko,
    unsigned short* __restrict__ Vo)
{
    __shared__ unsigned short smem[65536];   // 128 KiB

    const int t = threadIdx.x;
    const int wave = t >> 6, lane = t & 63;

    const int gx = gridDim.x;
    const int nwg = gx * gridDim.y;
    const int id0 = blockIdx.y * gx + blockIdx.x;
    const int cpx = nwg >> 3;
    const int swzid = (id0 & 7) * cpx + (id0 >> 3);
    const int bx = swzid % gx, by = swzid / gx;

    const int row0 = by * 256, col0 = bx * 256;
    const int wave_m = wave >> 2, wave_n = wave & 3;

    const unsigned short* Bp = Bt;

    const int fr  = lane & 15;
    const int fqb = (lane >> 4) << 4;
    const int sm  = (fr & 7) << 4;
    const int ck0 = ((0  + fqb) ^ sm) >> 1;
    const int ck1 = ((64 + fqb) ^ sm) >> 1;
    const int aRow = (wave_m * 128 + fr) * 64;
    const int bRow = (wave_n * 64 + fr) * 64;

    int srow[2], scol[2];
#pragma unroll
    for (int e = 0; e < 2; e++) {
        const int P  = (wave << 10) + (lane << 4) + (e << 13);
        const int r  = P >> 7;
        const int pc = P & 127;
        srow[e] = r;
        scol[e] = (pc ^ ((r & 7) << 4)) >> 1;
    }

    auto STAGE_PART = [&](int kt, int buf, int part) {
        const int isB = part >> 1, half = part & 1;
        const unsigned short* p = isB ? Bp : A;
        const int r0 = isB ? col0 : row0;
        const int ld = isB ? ldb : lda;
        const int ldsOff = buf * 32768 + isB * 16384 + half * 8192 + wave * 512;
#pragma unroll
        for (int e = 0; e < 2; e++)
            gload_lds16(&p[(size_t)(r0 + half * 128 + srow[e]) * ld
                           + ((kt & 15) << 6) + scol[e]],
                        &smem[ldsOff + e * 4096]);
    };

    floatx4 acc[8][4];
#pragma unroll
    for (int i = 0; i < 8; i++)
#pragma unroll
        for (int j = 0; j < 4; j++) acc[i][j] = (floatx4)0.0f;

    short8 a[4][2], bl[2][2], bh[2][2];

#define RDA(BUF, IH)                                                          \
    _Pragma("unroll") for (int ii = 0; ii < 4; ii++) {                        \
        a[ii][0] = *reinterpret_cast<const short8*>(                          \
            &smem[(BUF) * 32768 + aRow + ((IH) * 64 + ii * 16) * 64 + ck0]);  \
        a[ii][1] = *reinterpret_cast<const short8*>(                          \
            &smem[(BUF) * 32768 + aRow + ((IH) * 64 + ii * 16) * 64 + ck1]);  \
    }
#define RDB(BUF, JH, DST)                                                     \
    _Pragma("unroll") for (int jj = 0; jj < 2; jj++) {                        \
        DST[jj][0] = *reinterpret_cast<const short8*>(                        \
            &smem[(BUF) * 32768 + 16384 + bRow + ((JH) * 32 + jj * 16) * 64 + ck0]); \
        DST[jj][1] = *reinterpret_cast<const short8*>(                        \
            &smem[(BUF) * 32768 + 16384 + bRow + ((JH) * 32 + jj * 16) * 64 + ck1]); \
    }
#define MFMA_Q(IH, JH, BB)                                                    \
    __builtin_amdgcn_s_setprio(1);                                            \
    _Pragma("unroll") for (int ii = 0; ii < 4; ii++)                          \
    _Pragma("unroll") for (int jj = 0; jj < 2; jj++) {                        \
        acc[(IH)*4+ii][(JH)*2+jj] = __builtin_amdgcn_mfma_f32_16x16x32_bf16(  \
            a[ii][0], BB[jj][0], acc[(IH)*4+ii][(JH)*2+jj], 0, 0, 0);         \
        acc[(IH)*4+ii][(JH)*2+jj] = __builtin_amdgcn_mfma_f32_16x16x32_bf16(  \
            a[ii][1], BB[jj][1], acc[(IH)*4+ii][(JH)*2+jj], 0, 0, 0);         \
    }                                                                         \
    __builtin_amdgcn_s_setprio(0);
#define BARRIER __builtin_amdgcn_s_barrier()
#define WAIT_LGKM asm volatile("s_waitcnt lgkmcnt(0)" ::: "memory")
#define WAIT_VM2  asm volatile("s_waitcnt vmcnt(2)" ::: "memory")

#define KTILE(CUR, OTH, TN, TX)                                               \
    {                                                                         \
        RDA(CUR, 0); RDB(CUR, 0, bl);                                         \
        STAGE_PART(TN, OTH, 1);                                               \
        BARRIER; WAIT_LGKM; MFMA_Q(0, 0, bl); BARRIER;                        \
        RDB(CUR, 1, bh);                                                      \
        STAGE_PART(TN, OTH, 2);                                               \
        BARRIER; WAIT_LGKM; MFMA_Q(0, 1, bh); BARRIER;                        \
        RDA(CUR, 1);                                                          \
        STAGE_PART(TN, OTH, 3);                                               \
        BARRIER; WAIT_LGKM; MFMA_Q(1, 1, bh); BARRIER;                        \
        STAGE_PART(TX, CUR, 0);                                               \
        WAIT_VM2;                                                             \
        BARRIER;                                                              \
        MFMA_Q(1, 0, bl);                                                     \
        BARRIER;                                                              \
    }

    STAGE_PART(0, 0, 0); STAGE_PART(0, 0, 1);
    STAGE_PART(0, 0, 2); STAGE_PART(0, 0, 3);
    STAGE_PART(1, 1, 0);
    WAIT_VM2;
    BARRIER;

#pragma unroll 1
    for (int it = 0; it < 8; it++) {
        const int t1 = 2 * it + 1, t2 = 2 * it + 2, t3 = 2 * it + 3;
        KTILE(0, 1, t1, t2);
        KTILE(1, 0, t2, t3);
    }

#undef KTILE
#undef WAIT_VM2
#undef WAIT_LGKM
#undef BARRIER
#undef MFMA_Q
#undef RDB
#undef RDA

    const int cn = lane & 15, cq = (lane >> 4) * 4;

    __syncthreads();   // drains vmcnt/lgkmcnt + barrier before smem reuse

#pragma unroll
    for (int j = 0; j < 4; j++) {
        const int colL = wave_n * 64 + j * 16 + cn;
        const float bv = bias[col0 + colL];
#pragma unroll
        for (int i = 0; i < 8; i++)
#pragma unroll
            for (int r = 0; r < 4; r++) {
                const int lr = wave_m * 128 + i * 16 + cq + r;
                smem[lr * 256 + (colL ^ ((lr & 7) << 3))] = f2bf(acc[i][j][r] + bv);
            }
    }
    __syncthreads();

    {
        unsigned short* outp = (bx < 4) ? Qo : ((bx < 8) ? Ko : Vo);
        const bool isQ = (bx < 4);
        const int R = t >> 1, half = t & 1;
        const size_t obase = (size_t)(row0 + R) * CC + (col0 & 1023) + half * 128;
        unsigned short* orow = &outp[obase];

#pragma unroll
        for (int g = 0; g < 2; g++) {
            short8 bufv[8];
            const int cbase = half * 16 + g * 8;
#pragma unroll
            for (int k = 0; k < 8; k++)
                bufv[k] = *reinterpret_cast<const short8*>(
                    &smem[R * 256 + (((cbase + k) ^ (R & 7)) << 3)]);
            if (isQ) {
                float v[64];
                float mx = -3.0e38f;
#pragma unroll
                for (int k = 0; k < 8; k++)
#pragma unroll
                    for (int e = 0; e < 8; e++) {
                        const float f = bf2f((unsigned short)bufv[k][e]);
                        v[k * 8 + e] = f;
                        mx = fmaxf(mx, f);
                    }
                float s = 0.0f;
#pragma unroll
                for (int q = 0; q < 64; q++) {
                    const float ev = __expf(v[q] - mx);
                    v[q] = ev;
                    s += ev;
                }
                const float inv = 1.0f / s;
#pragma unroll
                for (int k = 0; k < 8; k++)
#pragma unroll
                    for (int e = 0; e < 8; e++)
                        bufv[k][e] = (short)f2bf(v[k * 8 + e] * inv);
            }
#pragma unroll
            for (int k = 0; k < 8; k++)
                *reinterpret_cast<short8*>(&orow[g * 64 + k * 8]) = bufv[k];
        }
    }
}

// ---------------------------------------------------------------------------
// Out GEMM (R6): IDENTICAL 256x256 8-phase main loop as QKV (16 MFMA/phase —
// R5's BN=128 halved MFMA per phase, doubling barrier overhead per FLOP).
// Grid 4x64 = 256 blocks = exactly 1/CU, single generation.
// B = per-batch WeffT (selected by row0>>12). fp32 direct store + bias.
// ---------------------------------------------------------------------------
__global__ __launch_bounds__(512) void gemm_out_kernel(
    const unsigned short* __restrict__ A, int lda,
    const unsigned short* __restrict__ Bt, int ldb,
    const float* __restrict__ bias,
    float* __restrict__ Cf, int ldc)
{
    __shared__ unsigned short smem[65536];   // 128 KiB

    const int t = threadIdx.x;
    const int wave = t >> 6, lane = t & 63;

    const int gx = gridDim.x;                 // 4
    const int nwg = gx * gridDim.y;           // 256
    const int id0 = blockIdx.y * gx + blockIdx.x;
    const int cpx = nwg >> 3;
    const int swzid = (id0 & 7) * cpx + (id0 >> 3);
    const int bx = swzid % gx, by = swzid / gx;

    const int row0 = by * 256, col0 = bx * 256;
    const int wave_m = wave >> 2, wave_n = wave & 3;

    const unsigned short* Bp = Bt + (((size_t)(row0 >> 12)) << 20);

    const int fr  = lane & 15;
    const int fqb = (lane >> 4) << 4;
    const int sm  = (fr & 7) << 4;
    const int ck0 = ((0  + fqb) ^ sm) >> 1;
    const int ck1 = ((64 + fqb) ^ sm) >> 1;
    const int aRow = (wave_m * 128 + fr) * 64;
    const int bRow = (wave_n * 64 + fr) * 64;

    int srow[2], scol[2];
#pragma unroll
    for (int e = 0; e < 2; e++) {
        const int P  = (wave << 10) + (lane << 4) + (e << 13);
        const int r  = P >> 7;
        const int pc = P & 127;
        srow[e] = r;
        scol[e] = (pc ^ ((r & 7) << 4)) >> 1;
    }

    auto STAGE_PART = [&](int kt, int buf, int part) {
        const int isB = part >> 1, half = part & 1;
        const unsigned short* p = isB ? Bp : A;
        const int r0 = isB ? col0 : row0;
        const int ld = isB ? ldb : lda;
        const int ldsOff = buf * 32768 + isB * 16384 + half * 8192 + wave * 512;
#pragma unroll
        for (int e = 0; e < 2; e++)
            gload_lds16(&p[(size_t)(r0 + half * 128 + srow[e]) * ld
                           + ((kt & 15) << 6) + scol[e]],
                        &smem[ldsOff + e * 4096]);
    };

    floatx4 acc[8][4];
#pragma unroll
    for (int i = 0; i < 8; i++)
#pragma unroll
        for (int j = 0; j < 4; j++) acc[i][j] = (floatx4)0.0f;

    short8 a[4][2], bl[2][2], bh[2][2];

#define RDA(BUF, IH)                                                          \
    _Pragma("unroll") for (int ii = 0; ii < 4; ii++) {                        \
        a[ii][0] = *reinterpret_cast<const short8*>(                          \
            &smem[(BUF) * 32768 + aRow + ((IH) * 64 + ii * 16) * 64 + ck0]);  \
        a[ii][1] = *reinterpret_cast<const short8*>(                          \
            &smem[(BUF) * 32768 + aRow + ((IH) * 64 + ii * 16) * 64 + ck1]);  \
    }
#define RDB(BUF, JH, DST)                                                     \
    _Pragma("unroll") for (int jj = 0; jj < 2; jj++) {                        \
        DST[jj][0] = *reinterpret_cast<const short8*>(                        \
            &smem[(BUF) * 32768 + 16384 + bRow + ((JH) * 32 + jj * 16) * 64 + ck0]); \
        DST[jj][1] = *reinterpret_cast<const short8*>(                        \
            &smem[(BUF) * 32768 + 16384 + bRow + ((JH) * 32 + jj * 16) * 64 + ck1]); \
    }
#define MFMA_Q(IH, JH, BB)                                                    \
    __builtin_amdgcn_s_setprio(1);                                            \
    _Pragma("unroll") for (int ii = 0; ii < 4; ii++)                          \
    _Pragma("unroll") for (int jj = 0; jj < 2; jj++) {                        \
        acc[(IH)*4+ii][(JH)*2+jj] = __builtin_amdgcn_mfma_f32_16x16x32_bf16(  \
            a[ii][0], BB[jj][0], acc[(IH)*4+ii][(JH)*2+jj], 0, 0, 0);         \
        acc[(IH)*4+ii][(JH)*2+jj] = __builtin_amdgcn_mfma_f32_16x16x32_bf16(  \
            a[ii][1], BB[jj][1], acc[(IH)*4+ii][(JH)*2+jj], 0, 0, 0);         \
    }                                                                         \
    __builtin_amdgcn_s_setprio(0);
#define BARRIER __builtin_amdgcn_s_barrier()
#define WAIT_LGKM asm volatile("s_waitcnt lgkmcnt(0)" ::: "memory")
#define WAIT_VM2  asm volatile("s_waitcnt vmcnt(2)" ::: "memory")

#define KTILE(CUR, OTH, TN, TX)                                               \
    {                                                                         \
        RDA(CUR, 0); RDB(CUR, 0, bl);                                         \
        STAGE_PART(TN, OTH, 1);                                               \
        BARRIER; WAIT_LGKM; MFMA_Q(0, 0, bl); BARRIER;                        \
        RDB(CUR, 1, bh);                                                      \
        STAGE_PART(TN, OTH, 2);                                               \
        BARRIER; WAIT_LGKM; MFMA_Q(0, 1, bh); BARRIER;                        \
        RDA(CUR, 1);                                                          \
        STAGE_PART(TN, OTH, 3);                                               \
        BARRIER; WAIT_LGKM; MFMA_Q(1, 1, bh); BARRIER;                        \
        STAGE_PART(TX, CUR, 0);                                               \
        WAIT_VM2;                                                             \
        BARRIER;                                                              \
        MFMA_Q(1, 0, bl);                                                     \
        BARRIER;                                                              \
    }

    STAGE_PART(0, 0, 0); STAGE_PART(0, 0, 1);
    STAGE_PART(0, 0, 2); STAGE_PART(0, 0, 3);
    STAGE_PART(1, 1, 0);
    WAIT_VM2;
    BARRIER;

#pragma unroll 1
    for (int it = 0; it < 8; it++) {
        const int t1 = 2 * it + 1, t2 = 2 * it + 2, t3 = 2 * it + 3;
        KTILE(0, 1, t1, t2);
        KTILE(1, 0, t2, t3);
    }

#undef KTILE
#undef WAIT_VM2
#undef WAIT_LGKM
#undef BARRIER
#undef MFMA_Q
#undef RDB
#undef RDA

    // fp32 direct store: 16 lanes cover a full 64B segment per (i,j,r)
    const int cn = lane & 15, cq = (lane >> 4) * 4;
#pragma unroll
    for (int j = 0; j < 4; j++) {
        const int col = col0 + wave_n * 64 + j * 16 + cn;
        const float bv = bias[col];
#pragma unroll
        for (int i = 0; i < 8; i++)
#pragma unroll
            for (int r = 0; r < 4; r++) {
                const int row = row0 + wave_m * 128 + i * 16 + cq + r;
                Cf[(size_t)row * ldc + col] = acc[i][j][r] + bv;
            }
    }
}

// ---------------------------------------------------------------------------
// Single-pass K/V context, atomic-free. R6: 8 chunks of 512 tokens (was 16x256)
// -> halves partial traffic; same VALU work.
// ---------------------------------------------------------------------------
__global__ __launch_bounds__(256) void kv_ctx_kernel(
    const unsigned short* __restrict__ Km, const unsigned short* __restrict__ Vm,
    float* __restrict__ ctx_p, float* __restrict__ csum_p)
{
    const int bh = blockIdx.x, ch = blockIdx.y;
    const int b = bh >> 4, h = bh & 15;
    const int t = threadIdx.x;

    __shared__ float Ks[32][68];
    __shared__ float Vs[32][68];
    __shared__ float cred[4][64];

    const int d0 = (t >> 4) * 4, e0 = (t & 15) * 4;
    float acc[4][4];
#pragma unroll
    for (int i = 0; i < 4; i++)
#pragma unroll
        for (int j = 0; j < 4; j++) acc[i][j] = 0.0f;
    float csacc = 0.0f;
    const int dc = t & 63, rq = (t >> 6) * 8;

    const size_t base = (size_t)(b * SEQ + ch * 512) * CC + (size_t)h * 64;
    const int lr = t >> 3, lc = (t & 7) * 8;   // staging: 16 B/lane

    for (int n0 = 0; n0 < 512; n0 += 32) {
        __syncthreads();
        {
            short8 k8 = *reinterpret_cast<const short8*>(&Km[base + (size_t)(n0 + lr) * CC + lc]);
            short8 v8 = *reinterpret_cast<const short8*>(&Vm[base + (size_t)(n0 + lr) * CC + lc]);
            float4 ka, kb, va, vb;
            ka.x = __expf(bf2f((unsigned short)k8[0]));
            ka.y = __expf(bf2f((unsigned short)k8[1]));
            ka.z = __expf(bf2f((unsigned short)k8[2]));
            ka.w = __expf(bf2f((unsigned short)k8[3]));
            kb.x = __expf(bf2f((unsigned short)k8[4]));
            kb.y = __expf(bf2f((unsigned short)k8[5]));
            kb.z = __expf(bf2f((unsigned short)k8[6]));
            kb.w = __expf(bf2f((unsigned short)k8[7]));
            va.x = bf2f((unsigned short)v8[0]); va.y = bf2f((unsigned short)v8[1]);
            va.z = bf2f((unsigned short)v8[2]); va.w = bf2f((unsigned short)v8[3]);
            vb.x = bf2f((unsigned short)v8[4]); vb.y = bf2f((unsigned short)v8[5]);
            vb.z = bf2f((unsigned short)v8[6]); vb.w = bf2f((unsigned short)v8[7]);
            *reinterpret_cast<float4*>(&Ks[lr][lc])     = ka;
            *reinterpret_cast<float4*>(&Ks[lr][lc + 4]) = kb;
            *reinterpret_cast<float4*>(&Vs[lr][lc])     = va;
            *reinterpret_cast<float4*>(&Vs[lr][lc + 4]) = vb;
        }
        __syncthreads();

#pragma unroll
        for (int r = 0; r < 8; r++) csacc += Ks[rq + r][dc];

#pragma unroll 8
        for (int n = 0; n < 32; n++) {
            float4 a = *reinterpret_cast<const float4*>(&Ks[n][d0]);
            float4 v4 = *reinterpret_cast<const float4*>(&Vs[n][e0]);
            float a4[4] = {a.x, a.y, a.z, a.w};
            float b4[4] = {v4.x, v4.y, v4.z, v4.w};
#pragma unroll
            for (int i = 0; i < 4; i++)
#pragma unroll
                for (int j = 0; j < 4; j++)
                    acc[i][j] += a4[i] * b4[j];
        }
    }

    __syncthreads();
    cred[t >> 6][dc] = csacc;
    __syncthreads();

    const size_t pslot = (size_t)ch * 64 + bh;
    if (t < 64)
        csum_p[pslot * 64 + t] =
            cred[0][t] + cred[1][t] + cred[2][t] + cred[3][t];

    float* cp = &ctx_p[pslot * 4096];
#pragma unroll
    for (int i = 0; i < 4; i++) {
        float4 v4;
        v4.x = acc[i][0]; v4.y = acc[i][1]; v4.z = acc[i][2]; v4.w = acc[i][3];
        *reinterpret_cast<float4*>(&cp[(d0 + i) * 64 + e0]) = v4;
    }
}

// ---------------------------------------------------------------------------
// Reduce the 8 chunk-partials: ctx[bh][4096] = sum_p ctx_p[p][bh][4096].
// ---------------------------------------------------------------------------
__global__ __launch_bounds__(256) void reduce_ctx_kernel(
    const float* __restrict__ ctx_p, const float* __restrict__ csum_p,
    float* __restrict__ ctx, float* __restrict__ csum)
{
    const int bh = blockIdx.x, q = blockIdx.y;
    const int t = threadIdx.x;
#pragma unroll
    for (int e = 0; e < 4; e++) {
        const int idx = (q * 4 + e) * 256 + t;
        float s = 0.0f;
#pragma unroll
        for (int p = 0; p < 8; p++)
            s += ctx_p[((size_t)p * 64 + bh) * 4096 + idx];
        ctx[(size_t)bh * 4096 + idx] = s;
    }
    if (q == 0 && t < 64) {
        float s = 0.0f;
#pragma unroll
        for (int p = 0; p < 8; p++)
            s += csum_p[((size_t)p * 64 + bh) * 64 + t];
        csum[(size_t)bh * 64 + t] = s;
    }
}

// ---------------------------------------------------------------------------
// W_eff build: WeffT[b][n][h*64+d] = f2bf((1/csum[bh,d]) *
//     sum_e ctx[b,h,d,e] * Wp[h*64+e, n])
// ctx staged transposed [e][d] (pad 68) + Wp slice [e][128]; thread owns
// 8d x 4n outer product: per e = 3 ds_read_b128 + 32 FMA.
// ---------------------------------------------------------------------------
__global__ __launch_bounds__(256) void weff_kernel(
    const float* __restrict__ ctx, const float* __restrict__ csum,
    const float* __restrict__ Wp, unsigned short* __restrict__ WeffT)
{
    const int bh = blockIdx.x, nc = blockIdx.y;
    const int b = bh >> 4, h = bh & 15;
    const int t = threadIdx.x;

    __shared__ float ctxsT[64 * 68];   // [e][d], pad 68
    __shared__ float WpS[64 * 128];    // [e][n']
    __shared__ float cinvs[64];

#pragma unroll
    for (int l = 0; l < 16; l++) {
        const int idx = t + l * 256;            // idx = d*64 + e
        ctxsT[(idx & 63) * 68 + (idx >> 6)] = ctx[(size_t)bh * 4096 + idx];
    }
#pragma unroll
    for (int l = 0; l < 32; l++) {
        const int idx = t + l * 256;            // idx = e*128 + n'
        WpS[idx] = Wp[(size_t)(h * 64 + (idx >> 7)) * CC + nc * 128 + (idx & 127)];
    }
    if (t < 64) cinvs[t] = 1.0f / csum[(size_t)bh * 64 + t];
    __syncthreads();

    const int d0 = (t >> 5) * 8;     // 8 d-groups of 8
    const int n0 = (t & 31) * 4;     // 32 n-groups of 4

    float acc[8][4];
#pragma unroll
    for (int i = 0; i < 8; i++)
#pragma unroll
        for (int j = 0; j < 4; j++) acc[i][j] = 0.0f;

#pragma unroll 4
    for (int e = 0; e < 64; e++) {
        float4 c0 = *reinterpret_cast<const float4*>(&ctxsT[e * 68 + d0]);
        float4 c1 = *reinterpret_cast<const float4*>(&ctxsT[e * 68 + d0 + 4]);
        float4 w4 = *reinterpret_cast<const float4*>(&WpS[e * 128 + n0]);
        const float cc[8] = {c0.x, c0.y, c0.z, c0.w, c1.x, c1.y, c1.z, c1.w};
        const float ww[4] = {w4.x, w4.y, w4.z, w4.w};
#pragma unroll
        for (int i = 0; i < 8; i++)
#pragma unroll
            for (int j = 0; j < 4; j++)
                acc[i][j] += cc[i] * ww[j];
    }

    const size_t obase = ((size_t)b << 20) + (size_t)(nc * 128 + n0) * CC + h * 64 + d0;
#pragma unroll
    for (int j = 0; j < 4; j++) {
        short8 o;
#pragma unroll
        for (int i = 0; i < 8; i++)
            o[i] = (short)f2bf(acc[i][j] * cinvs[d0 + i]);
        *reinterpret_cast<short8*>(&WeffT[obase + (size_t)j * CC]) = o;
    }
}

// ---------------------------------------------------------------------------
extern "C" void kernel_launch(void* const* d_in, const int* in_sizes, int n_in,
                              void* d_out, int out_size, void* d_ws, size_t ws_size,
                              hipStream_t stream)
{
    const float* x      = (const float*)d_in[0];
    const float* W_qkv  = (const float*)d_in[1];
    const float* b_qkv  = (const float*)d_in[2];
    const float* W_proj = (const float*)d_in[3];
    const float* b_proj = (const float*)d_in[4];
    float* out = (float*)d_out;

    // Workspace layout — same footprint as the R2/R4/R5-passing runs (~150 MB).
    // ctx_p/csum_p (8.5 MB) alias xb (33.5 MB): xb dead after QKV GEMM;
    // partials live only across dispatches 2-3. Stream-ordered.
    unsigned short* Qm  = (unsigned short*)d_ws;               // [16384,1024] bf16
    unsigned short* Km  = Qm + (size_t)TOKENS * CC;
    unsigned short* Vm  = Km + (size_t)TOKENS * CC;
    unsigned short* xb  = Vm + (size_t)TOKENS * CC;            // x bf16 (dead after QKV)
    unsigned short* wqT = xb + (size_t)TOKENS * CC;            // [3072,1024]
    unsigned short* WeffT = wqT + (size_t)QKV3 * CC;           // [4,1024,1024] bf16
    float* ctx    = (float*)(WeffT + (size_t)BBATCH * CC * CC);// [64,4096] fp32
    float* csum   = ctx + (size_t)64 * 4096;                   // [64,64]
    float* ctx_p  = (float*)xb;                                // [8,64,4096] (aliases xb)
    float* csum_p = ctx_p + (size_t)8 * 64 * 4096;             // [8,64,64]   (still in xb)

    // 0) x -> bf16; W_qkv -> bf16 transposed
    cvt_bf16_kernel<<<(TOKENS * CC / 4 + 255) / 256, 256, 0, stream>>>(
        x, xb, (long)TOKENS * CC / 4);
    transpose_bf16_kernel<<<dim3(QKV3 / 32, CC / 32), 256, 0, stream>>>(
        W_qkv, CC, QKV3, wqT);

    // 1) QKV GEMM -> Q / K / V bf16 (fused Q softmax epilogue)
    gemm_qkv_kernel<<<dim3(QKV3 / 256, TOKENS / 256), 512, 0, stream>>>(
        xb, CC, wqT, CC, b_qkv, Qm, Km, Vm);

    // 2) single-pass exp(K)/V -> per-chunk partials (no atomics)
    kv_ctx_kernel<<<dim3(BBATCH * HH, 8), 256, 0, stream>>>(Km, Vm, ctx_p, csum_p);

    // 3) reduce partials -> ctx, csum
    reduce_ctx_kernel<<<dim3(BBATCH * HH, 4), 256, 0, stream>>>(
        ctx_p, csum_p, ctx, csum);

    // 4) effective projection weights per batch (applies 1/csum)
    weff_kernel<<<dim3(BBATCH * HH, 8), 256, 0, stream>>>(ctx, csum, W_proj, WeffT);

    // 5) out = Qhat @ WeffT[batch] + b_proj (256^2 8-phase, 1 block/CU)
    gemm_out_kernel<<<dim3(CC / 256, TOKENS / 256), 512, 0, stream>>>(
        Qm, CC, WeffT, CC, b_proj, out, CC);
}

// Round 7
// 351.257 us; speedup vs baseline: 1.2985x; 1.0234x over previous
//
#include <hip/hip_runtime.h>

// Problem constants
#define BBATCH 4
#define SEQ 4096
#define CC 1024
#define HH 16
#define DD 64
#define TOKENS 16384              // B*N
#define QKV3 3072                 // 3*C

typedef __attribute__((ext_vector_type(8))) short short8;
typedef __attribute__((ext_vector_type(4))) float floatx4;

// bf16 helpers (RNE)
__device__ __forceinline__ unsigned short f2bf(float x) {
    unsigned int u = __float_as_uint(x);
    u += 0x7fff + ((u >> 16) & 1);
    return (unsigned short)(u >> 16);
}
__device__ __forceinline__ float bf2f(unsigned short h) {
    return __uint_as_float((unsigned int)h << 16);
}

__device__ __forceinline__ void gload_lds16(const void* g, void* l) {
    __builtin_amdgcn_global_load_lds(
        (const __attribute__((address_space(1))) unsigned int*)g,
        (__attribute__((address_space(3))) unsigned int*)l, 16, 0, 0);
}

// ---------------------------------------------------------------------------
// prep: fused (x fp32 -> bf16) + (W_qkv transpose -> bf16). One dispatch.
// blocks [0, 16384): cvt; blocks [16384, 19456): 32x32 transpose tiles.
// ---------------------------------------------------------------------------
__global__ __launch_bounds__(256) void prep_kernel(
    const float* __restrict__ X, unsigned short* __restrict__ Y,
    const float* __restrict__ W, unsigned short* __restrict__ T)
{
    __shared__ unsigned short Lh[32][36];
    const int t = threadIdx.x;
    const int b = blockIdx.x;

    if (b < 16384) {
        const long i = (long)b * 256 + t;
        float4 v = *reinterpret_cast<const float4*>(&X[i * 4]);
        ushort4 h;
        h.x = f2bf(v.x); h.y = f2bf(v.y); h.z = f2bf(v.z); h.w = f2bf(v.w);
        *reinterpret_cast<ushort4*>(&Y[i * 4]) = h;
        return;
    }

    const int bb = b - 16384;                 // [0, 3072)
    const int n0 = (bb % 96) * 32;            // QKV3/32 = 96
    const int k0 = (bb / 96) * 32;            // CC/32 = 32
    const int r = t >> 3, c4 = (t & 7) * 4;

    float4 w = *reinterpret_cast<const float4*>(&W[(size_t)(k0 + r) * QKV3 + n0 + c4]);
    Lh[r][c4 + 0] = f2bf(w.x);
    Lh[r][c4 + 1] = f2bf(w.y);
    Lh[r][c4 + 2] = f2bf(w.z);
    Lh[r][c4 + 3] = f2bf(w.w);
    __syncthreads();

    const int rn = t >> 3, ck = (t & 7) * 4;
    ushort4 h4;
    h4.x = Lh[ck + 0][rn]; h4.y = Lh[ck + 1][rn];
    h4.z = Lh[ck + 2][rn]; h4.w = Lh[ck + 3][rn];
    *reinterpret_cast<ushort4*>(&T[(size_t)(n0 + rn) * CC + k0 + ck]) = h4;
}

// ---------------------------------------------------------------------------
// QKV GEMM: 256x256 8-phase bf16 (unchanged: 134 us, MfmaUtil 32%).
// Epilogue: acc+bias -> swizzled LDS, coalesced ushort8 store, fused Q softmax.
// ---------------------------------------------------------------------------
__global__ __launch_bounds__(512) void gemm_qkv_kernel(
    const unsigned short* __restrict__ A, int lda,
    const unsigned short* __restrict__ Bt, int ldb,
    const float* __restrict__ bias,
    unsigned short* __restrict__ Qo, unsigned short* __restrict__ Ko,
    unsigned short* __restrict__ Vo)
{
    __shared__ unsigned short smem[65536];   // 128 KiB

    const int t = threadIdx.x;
    const int wave = t >> 6, lane = t & 63;

    const int gx = gridDim.x;
    const int nwg = gx * gridDim.y;
    const int id0 = blockIdx.y * gx + blockIdx.x;
    const int cpx = nwg >> 3;
    const int swzid = (id0 & 7) * cpx + (id0 >> 3);
    const int bx = swzid % gx, by = swzid / gx;

    const int row0 = by * 256, col0 = bx * 256;
    const int wave_m = wave >> 2, wave_n = wave & 3;

    const unsigned short* Bp = Bt;

    const int fr  = lane & 15;
    const int fqb = (lane >> 4) << 4;
    const int sm  = (fr & 7) << 4;
    const int ck0 = ((0  + fqb) ^ sm) >> 1;
    const int ck1 = ((64 + fqb) ^ sm) >> 1;
    const int aRow = (wave_m * 128 + fr) * 64;
    const int bRow = (wave_n * 64 + fr) * 64;

    int srow[2], scol[2];
#pragma unroll
    for (int e = 0; e < 2; e++) {
        const int P  = (wave << 10) + (lane << 4) + (e << 13);
        const int r  = P >> 7;
        const int pc = P & 127;
        srow[e] = r;
        scol[e] = (pc ^ ((r & 7) << 4)) >> 1;
    }

    auto STAGE_PART = [&](int kt, int buf, int part) {
        const int isB = part >> 1, half = part & 1;
        const unsigned short* p = isB ? Bp : A;
        const int r0 = isB ? col0 : row0;
        const int ld = isB ? ldb : lda;
        const int ldsOff = buf * 32768 + isB * 16384 + half * 8192 + wave * 512;
#pragma unroll
        for (int e = 0; e < 2; e++)
            gload_lds16(&p[(size_t)(r0 + half * 128 + srow[e]) * ld
                           + ((kt & 15) << 6) + scol[e]],
                        &smem[ldsOff + e * 4096]);
    };

    floatx4 acc[8][4];
#pragma unroll
    for (int i = 0; i < 8; i++)
#pragma unroll
        for (int j = 0; j < 4; j++) acc[i][j] = (floatx4)0.0f;

    short8 a[4][2], bl[2][2], bh[2][2];

#define RDA(BUF, IH)                                                          \
    _Pragma("unroll") for (int ii = 0; ii < 4; ii++) {                        \
        a[ii][0] = *reinterpret_cast<const short8*>(                          \
            &smem[(BUF) * 32768 + aRow + ((IH) * 64 + ii * 16) * 64 + ck0]);  \
        a[ii][1] = *reinterpret_cast<const short8*>(                          \
            &smem[(BUF) * 32768 + aRow + ((IH) * 64 + ii * 16) * 64 + ck1]);  \
    }
#define RDB(BUF, JH, DST)                                                     \
    _Pragma("unroll") for (int jj = 0; jj < 2; jj++) {                        \
        DST[jj][0] = *reinterpret_cast<const short8*>(                        \
            &smem[(BUF) * 32768 + 16384 + bRow + ((JH) * 32 + jj * 16) * 64 + ck0]); \
        DST[jj][1] = *reinterpret_cast<const short8*>(                        \
            &smem[(BUF) * 32768 + 16384 + bRow + ((JH) * 32 + jj * 16) * 64 + ck1]); \
    }
#define MFMA_Q(IH, JH, BB)                                                    \
    __builtin_amdgcn_s_setprio(1);                                            \
    _Pragma("unroll") for (int ii = 0; ii < 4; ii++)                          \
    _Pragma("unroll") for (int jj = 0; jj < 2; jj++) {                        \
        acc[(IH)*4+ii][(JH)*2+jj] = __builtin_amdgcn_mfma_f32_16x16x32_bf16(  \
            a[ii][0], BB[jj][0], acc[(IH)*4+ii][(JH)*2+jj], 0, 0, 0);         \
        acc[(IH)*4+ii][(JH)*2+jj] = __builtin_amdgcn_mfma_f32_16x16x32_bf16(  \
            a[ii][1], BB[jj][1], acc[(IH)*4+ii][(JH)*2+jj], 0, 0, 0);         \
    }                                                                         \
    __builtin_amdgcn_s_setprio(0);
#define BARRIER __builtin_amdgcn_s_barrier()
#define WAIT_LGKM asm volatile("s_waitcnt lgkmcnt(0)" ::: "memory")
#define WAIT_VM2  asm volatile("s_waitcnt vmcnt(2)" ::: "memory")

#define KTILE(CUR, OTH, TN, TX)                                               \
    {                                                                         \
        RDA(CUR, 0); RDB(CUR, 0, bl);                                         \
        STAGE_PART(TN, OTH, 1);                                               \
        BARRIER; WAIT_LGKM; MFMA_Q(0, 0, bl); BARRIER;                        \
        RDB(CUR, 1, bh);                                                      \
        STAGE_PART(TN, OTH, 2);                                               \
        BARRIER; WAIT_LGKM; MFMA_Q(0, 1, bh); BARRIER;                        \
        RDA(CUR, 1);                                                          \
        STAGE_PART(TN, OTH, 3);                                               \
        BARRIER; WAIT_LGKM; MFMA_Q(1, 1, bh); BARRIER;                        \
        STAGE_PART(TX, CUR, 0);                                               \
        WAIT_VM2;                                                             \
        BARRIER;                                                              \
        MFMA_Q(1, 0, bl);                                                     \
        BARRIER;                                                              \
    }

    STAGE_PART(0, 0, 0); STAGE_PART(0, 0, 1);
    STAGE_PART(0, 0, 2); STAGE_PART(0, 0, 3);
    STAGE_PART(1, 1, 0);
    WAIT_VM2;
    BARRIER;

#pragma unroll 1
    for (int it = 0; it < 8; it++) {
        const int t1 = 2 * it + 1, t2 = 2 * it + 2, t3 = 2 * it + 3;
        KTILE(0, 1, t1, t2);
        KTILE(1, 0, t2, t3);
    }

#undef KTILE
#undef WAIT_VM2
#undef WAIT_LGKM
#undef BARRIER
#undef MFMA_Q
#undef RDB
#undef RDA

    const int cn = lane & 15, cq = (lane >> 4) * 4;

    __syncthreads();   // drains vmcnt/lgkmcnt + barrier before smem reuse

#pragma unroll
    for (int j = 0; j < 4; j++) {
        const int colL = wave_n * 64 + j * 16 + cn;
        const float bv = bias[col0 + colL];
#pragma unroll
        for (int i = 0; i < 8; i++)
#pragma unroll
            for (int r = 0; r < 4; r++) {
                const int lr = wave_m * 128 + i * 16 + cq + r;
                smem[lr * 256 + (colL ^ ((lr & 7) << 3))] = f2bf(acc[i][j][r] + bv);
            }
    }
    __syncthreads();

    {
        unsigned short* outp = (bx < 4) ? Qo : ((bx < 8) ? Ko : Vo);
        const bool isQ = (bx < 4);
        const int R = t >> 1, half = t & 1;
        const size_t obase = (size_t)(row0 + R) * CC + (col0 & 1023) + half * 128;
        unsigned short* orow = &outp[obase];

#pragma unroll
        for (int g = 0; g < 2; g++) {
            short8 bufv[8];
            const int cbase = half * 16 + g * 8;
#pragma unroll
            for (int k = 0; k < 8; k++)
                bufv[k] = *reinterpret_cast<const short8*>(
                    &smem[R * 256 + (((cbase + k) ^ (R & 7)) << 3)]);
            if (isQ) {
                float v[64];
                float mx = -3.0e38f;
#pragma unroll
                for (int k = 0; k < 8; k++)
#pragma unroll
                    for (int e = 0; e < 8; e++) {
                        const float f = bf2f((unsigned short)bufv[k][e]);
                        v[k * 8 + e] = f;
                        mx = fmaxf(mx, f);
                    }
                float s = 0.0f;
#pragma unroll
                for (int q = 0; q < 64; q++) {
                    const float ev = __expf(v[q] - mx);
                    v[q] = ev;
                    s += ev;
                }
                const float inv = 1.0f / s;
#pragma unroll
                for (int k = 0; k < 8; k++)
#pragma unroll
                    for (int e = 0; e < 8; e++)
                        bufv[k][e] = (short)f2bf(v[k * 8 + e] * inv);
            }
#pragma unroll
            for (int k = 0; k < 8; k++)
                *reinterpret_cast<short8*>(&orow[g * 64 + k * 8]) = bufv[k];
        }
    }
}

// ---------------------------------------------------------------------------
// Out GEMM: 256x256 8-phase (unchanged from R6). 256 blocks = 1/CU.
// ---------------------------------------------------------------------------
__global__ __launch_bounds__(512) void gemm_out_kernel(
    const unsigned short* __restrict__ A, int lda,
    const unsigned short* __restrict__ Bt, int ldb,
    const float* __restrict__ bias,
    float* __restrict__ Cf, int ldc)
{
    __shared__ unsigned short smem[65536];   // 128 KiB

    const int t = threadIdx.x;
    const int wave = t >> 6, lane = t & 63;

    const int gx = gridDim.x;                 // 4
    const int nwg = gx * gridDim.y;           // 256
    const int id0 = blockIdx.y * gx + blockIdx.x;
    const int cpx = nwg >> 3;
    const int swzid = (id0 & 7) * cpx + (id0 >> 3);
    const int bx = swzid % gx, by = swzid / gx;

    const int row0 = by * 256, col0 = bx * 256;
    const int wave_m = wave >> 2, wave_n = wave & 3;

    const unsigned short* Bp = Bt + (((size_t)(row0 >> 12)) << 20);

    const int fr  = lane & 15;
    const int fqb = (lane >> 4) << 4;
    const int sm  = (fr & 7) << 4;
    const int ck0 = ((0  + fqb) ^ sm) >> 1;
    const int ck1 = ((64 + fqb) ^ sm) >> 1;
    const int aRow = (wave_m * 128 + fr) * 64;
    const int bRow = (wave_n * 64 + fr) * 64;

    int srow[2], scol[2];
#pragma unroll
    for (int e = 0; e < 2; e++) {
        const int P  = (wave << 10) + (lane << 4) + (e << 13);
        const int r  = P >> 7;
        const int pc = P & 127;
        srow[e] = r;
        scol[e] = (pc ^ ((r & 7) << 4)) >> 1;
    }

    auto STAGE_PART = [&](int kt, int buf, int part) {
        const int isB = part >> 1, half = part & 1;
        const unsigned short* p = isB ? Bp : A;
        const int r0 = isB ? col0 : row0;
        const int ld = isB ? ldb : lda;
        const int ldsOff = buf * 32768 + isB * 16384 + half * 8192 + wave * 512;
#pragma unroll
        for (int e = 0; e < 2; e++)
            gload_lds16(&p[(size_t)(r0 + half * 128 + srow[e]) * ld
                           + ((kt & 15) << 6) + scol[e]],
                        &smem[ldsOff + e * 4096]);
    };

    floatx4 acc[8][4];
#pragma unroll
    for (int i = 0; i < 8; i++)
#pragma unroll
        for (int j = 0; j < 4; j++) acc[i][j] = (floatx4)0.0f;

    short8 a[4][2], bl[2][2], bh[2][2];

#define RDA(BUF, IH)                                                          \
    _Pragma("unroll") for (int ii = 0; ii < 4; ii++) {                        \
        a[ii][0] = *reinterpret_cast<const short8*>(                          \
            &smem[(BUF) * 32768 + aRow + ((IH) * 64 + ii * 16) * 64 + ck0]);  \
        a[ii][1] = *reinterpret_cast<const short8*>(                          \
            &smem[(BUF) * 32768 + aRow + ((IH) * 64 + ii * 16) * 64 + ck1]);  \
    }
#define RDB(BUF, JH, DST)                                                     \
    _Pragma("unroll") for (int jj = 0; jj < 2; jj++) {                        \
        DST[jj][0] = *reinterpret_cast<const short8*>(                        \
            &smem[(BUF) * 32768 + 16384 + bRow + ((JH) * 32 + jj * 16) * 64 + ck0]); \
        DST[jj][1] = *reinterpret_cast<const short8*>(                        \
            &smem[(BUF) * 32768 + 16384 + bRow + ((JH) * 32 + jj * 16) * 64 + ck1]); \
    }
#define MFMA_Q(IH, JH, BB)                                                    \
    __builtin_amdgcn_s_setprio(1);                                            \
    _Pragma("unroll") for (int ii = 0; ii < 4; ii++)                          \
    _Pragma("unroll") for (int jj = 0; jj < 2; jj++) {                        \
        acc[(IH)*4+ii][(JH)*2+jj] = __builtin_amdgcn_mfma_f32_16x16x32_bf16(  \
            a[ii][0], BB[jj][0], acc[(IH)*4+ii][(JH)*2+jj], 0, 0, 0);         \
        acc[(IH)*4+ii][(JH)*2+jj] = __builtin_amdgcn_mfma_f32_16x16x32_bf16(  \
            a[ii][1], BB[jj][1], acc[(IH)*4+ii][(JH)*2+jj], 0, 0, 0);         \
    }                                                                         \
    __builtin_amdgcn_s_setprio(0);
#define BARRIER __builtin_amdgcn_s_barrier()
#define WAIT_LGKM asm volatile("s_waitcnt lgkmcnt(0)" ::: "memory")
#define WAIT_VM2  asm volatile("s_waitcnt vmcnt(2)" ::: "memory")

#define KTILE(CUR, OTH, TN, TX)                                               \
    {                                                                         \
        RDA(CUR, 0); RDB(CUR, 0, bl);                                         \
        STAGE_PART(TN, OTH, 1);                                               \
        BARRIER; WAIT_LGKM; MFMA_Q(0, 0, bl); BARRIER;                        \
        RDB(CUR, 1, bh);                                                      \
        STAGE_PART(TN, OTH, 2);                                               \
        BARRIER; WAIT_LGKM; MFMA_Q(0, 1, bh); BARRIER;                        \
        RDA(CUR, 1);                                                          \
        STAGE_PART(TN, OTH, 3);                                               \
        BARRIER; WAIT_LGKM; MFMA_Q(1, 1, bh); BARRIER;                        \
        STAGE_PART(TX, CUR, 0);                                               \
        WAIT_VM2;                                                             \
        BARRIER;                                                              \
        MFMA_Q(1, 0, bl);                                                     \
        BARRIER;                                                              \
    }

    STAGE_PART(0, 0, 0); STAGE_PART(0, 0, 1);
    STAGE_PART(0, 0, 2); STAGE_PART(0, 0, 3);
    STAGE_PART(1, 1, 0);
    WAIT_VM2;
    BARRIER;

#pragma unroll 1
    for (int it = 0; it < 8; it++) {
        const int t1 = 2 * it + 1, t2 = 2 * it + 2, t3 = 2 * it + 3;
        KTILE(0, 1, t1, t2);
        KTILE(1, 0, t2, t3);
    }

#undef KTILE
#undef WAIT_VM2
#undef WAIT_LGKM
#undef BARRIER
#undef MFMA_Q
#undef RDB
#undef RDA

    const int cn = lane & 15, cq = (lane >> 4) * 4;
#pragma unroll
    for (int j = 0; j < 4; j++) {
        const int col = col0 + wave_n * 64 + j * 16 + cn;
        const float bv = bias[col];
#pragma unroll
        for (int i = 0; i < 8; i++)
#pragma unroll
            for (int r = 0; r < 4; r++) {
                const int row = row0 + wave_m * 128 + i * 16 + cq + r;
                Cf[(size_t)row * ldc + col] = acc[i][j][r] + bv;
            }
    }
}

// ---------------------------------------------------------------------------
// Single-pass K/V context, atomic-free. 8 chunks of 512 tokens (unchanged).
// ---------------------------------------------------------------------------
__global__ __launch_bounds__(256) void kv_ctx_kernel(
    const unsigned short* __restrict__ Km, const unsigned short* __restrict__ Vm,
    float* __restrict__ ctx_p, float* __restrict__ csum_p)
{
    const int bh = blockIdx.x, ch = blockIdx.y;
    const int b = bh >> 4, h = bh & 15;
    const int t = threadIdx.x;

    __shared__ float Ks[32][68];
    __shared__ float Vs[32][68];
    __shared__ float cred[4][64];

    const int d0 = (t >> 4) * 4, e0 = (t & 15) * 4;
    float acc[4][4];
#pragma unroll
    for (int i = 0; i < 4; i++)
#pragma unroll
        for (int j = 0; j < 4; j++) acc[i][j] = 0.0f;
    float csacc = 0.0f;
    const int dc = t & 63, rq = (t >> 6) * 8;

    const size_t base = (size_t)(b * SEQ + ch * 512) * CC + (size_t)h * 64;
    const int lr = t >> 3, lc = (t & 7) * 8;   // staging: 16 B/lane

    for (int n0 = 0; n0 < 512; n0 += 32) {
        __syncthreads();
        {
            short8 k8 = *reinterpret_cast<const short8*>(&Km[base + (size_t)(n0 + lr) * CC + lc]);
            short8 v8 = *reinterpret_cast<const short8*>(&Vm[base + (size_t)(n0 + lr) * CC + lc]);
            float4 ka, kb, va, vb;
            ka.x = __expf(bf2f((unsigned short)k8[0]));
            ka.y = __expf(bf2f((unsigned short)k8[1]));
            ka.z = __expf(bf2f((unsigned short)k8[2]));
            ka.w = __expf(bf2f((unsigned short)k8[3]));
            kb.x = __expf(bf2f((unsigned short)k8[4]));
            kb.y = __expf(bf2f((unsigned short)k8[5]));
            kb.z = __expf(bf2f((unsigned short)k8[6]));
            kb.w = __expf(bf2f((unsigned short)k8[7]));
            va.x = bf2f((unsigned short)v8[0]); va.y = bf2f((unsigned short)v8[1]);
            va.z = bf2f((unsigned short)v8[2]); va.w = bf2f((unsigned short)v8[3]);
            vb.x = bf2f((unsigned short)v8[4]); vb.y = bf2f((unsigned short)v8[5]);
            vb.z = bf2f((unsigned short)v8[6]); vb.w = bf2f((unsigned short)v8[7]);
            *reinterpret_cast<float4*>(&Ks[lr][lc])     = ka;
            *reinterpret_cast<float4*>(&Ks[lr][lc + 4]) = kb;
            *reinterpret_cast<float4*>(&Vs[lr][lc])     = va;
            *reinterpret_cast<float4*>(&Vs[lr][lc + 4]) = vb;
        }
        __syncthreads();

#pragma unroll
        for (int r = 0; r < 8; r++) csacc += Ks[rq + r][dc];

#pragma unroll 8
        for (int n = 0; n < 32; n++) {
            float4 a = *reinterpret_cast<const float4*>(&Ks[n][d0]);
            float4 v4 = *reinterpret_cast<const float4*>(&Vs[n][e0]);
            float a4[4] = {a.x, a.y, a.z, a.w};
            float b4[4] = {v4.x, v4.y, v4.z, v4.w};
#pragma unroll
            for (int i = 0; i < 4; i++)
#pragma unroll
                for (int j = 0; j < 4; j++)
                    acc[i][j] += a4[i] * b4[j];
        }
    }

    __syncthreads();
    cred[t >> 6][dc] = csacc;
    __syncthreads();

    const size_t pslot = (size_t)ch * 64 + bh;
    if (t < 64)
        csum_p[pslot * 64 + t] =
            cred[0][t] + cred[1][t] + cred[2][t] + cred[3][t];

    float* cp = &ctx_p[pslot * 4096];
#pragma unroll
    for (int i = 0; i < 4; i++) {
        float4 v4;
        v4.x = acc[i][0]; v4.y = acc[i][1]; v4.z = acc[i][2]; v4.w = acc[i][3];
        *reinterpret_cast<float4*>(&cp[(d0 + i) * 64 + e0]) = v4;
    }
}

// ---------------------------------------------------------------------------
// W_eff build with FUSED partial-reduction (R7): reads the 8 chunk-partials
// directly (8x reads of an 8.5 MB L2-resident buffer), deleting the
// reduce_ctx dispatch. ctx staged transposed [e][d] (pad 68) + Wp [e][128];
// thread owns 8d x 4n outer product.
// ---------------------------------------------------------------------------
__global__ __launch_bounds__(256) void weff_kernel(
    const float* __restrict__ ctx_p, const float* __restrict__ csum_p,
    const float* __restrict__ Wp, unsigned short* __restrict__ WeffT)
{
    const int bh = blockIdx.x, nc = blockIdx.y;
    const int b = bh >> 4, h = bh & 15;
    const int t = threadIdx.x;

    __shared__ float ctxsT[64 * 68];   // [e][d], pad 68
    __shared__ float WpS[64 * 128];    // [e][n']
    __shared__ float cinvs[64];

#pragma unroll
    for (int l = 0; l < 16; l++) {
        const int idx = t + l * 256;            // idx = d*64 + e
        float s = 0.0f;
#pragma unroll
        for (int p = 0; p < 8; p++)
            s += ctx_p[((size_t)p * 64 + bh) * 4096 + idx];
        ctxsT[(idx & 63) * 68 + (idx >> 6)] = s;
    }
#pragma unroll
    for (int l = 0; l < 32; l++) {
        const int idx = t + l * 256;            // idx = e*128 + n'
        WpS[idx] = Wp[(size_t)(h * 64 + (idx >> 7)) * CC + nc * 128 + (idx & 127)];
    }
    if (t < 64) {
        float s = 0.0f;
#pragma unroll
        for (int p = 0; p < 8; p++)
            s += csum_p[((size_t)p * 64 + bh) * 64 + t];
        cinvs[t] = 1.0f / s;
    }
    __syncthreads();

    const int d0 = (t >> 5) * 8;     // 8 d-groups of 8
    const int n0 = (t & 31) * 4;     // 32 n-groups of 4

    float acc[8][4];
#pragma unroll
    for (int i = 0; i < 8; i++)
#pragma unroll
        for (int j = 0; j < 4; j++) acc[i][j] = 0.0f;

#pragma unroll 4
    for (int e = 0; e < 64; e++) {
        float4 c0 = *reinterpret_cast<const float4*>(&ctxsT[e * 68 + d0]);
        float4 c1 = *reinterpret_cast<const float4*>(&ctxsT[e * 68 + d0 + 4]);
        float4 w4 = *reinterpret_cast<const float4*>(&WpS[e * 128 + n0]);
        const float cc[8] = {c0.x, c0.y, c0.z, c0.w, c1.x, c1.y, c1.z, c1.w};
        const float ww[4] = {w4.x, w4.y, w4.z, w4.w};
#pragma unroll
        for (int i = 0; i < 8; i++)
#pragma unroll
            for (int j = 0; j < 4; j++)
                acc[i][j] += cc[i] * ww[j];
    }

    const size_t obase = ((size_t)b << 20) + (size_t)(nc * 128 + n0) * CC + h * 64 + d0;
#pragma unroll
    for (int j = 0; j < 4; j++) {
        short8 o;
#pragma unroll
        for (int i = 0; i < 8; i++)
            o[i] = (short)f2bf(acc[i][j] * cinvs[d0 + i]);
        *reinterpret_cast<short8*>(&WeffT[obase + (size_t)j * CC]) = o;
    }
}

// ---------------------------------------------------------------------------
extern "C" void kernel_launch(void* const* d_in, const int* in_sizes, int n_in,
                              void* d_out, int out_size, void* d_ws, size_t ws_size,
                              hipStream_t stream)
{
    const float* x      = (const float*)d_in[0];
    const float* W_qkv  = (const float*)d_in[1];
    const float* b_qkv  = (const float*)d_in[2];
    const float* W_proj = (const float*)d_in[3];
    const float* b_proj = (const float*)d_in[4];
    float* out = (float*)d_out;

    // Workspace layout — same footprint as R2/R4-R6 passing runs (~150 MB).
    // ctx_p/csum_p (8.5 MB) alias xb (33.5 MB): xb dead after QKV GEMM;
    // partials live only across dispatches 3-4. Stream-ordered.
    unsigned short* Qm  = (unsigned short*)d_ws;               // [16384,1024] bf16
    unsigned short* Km  = Qm + (size_t)TOKENS * CC;
    unsigned short* Vm  = Km + (size_t)TOKENS * CC;
    unsigned short* xb  = Vm + (size_t)TOKENS * CC;            // x bf16 (dead after QKV)
    unsigned short* wqT = xb + (size_t)TOKENS * CC;            // [3072,1024]
    unsigned short* WeffT = wqT + (size_t)QKV3 * CC;           // [4,1024,1024] bf16
    float* ctx_p  = (float*)xb;                                // [8,64,4096] (aliases xb)
    float* csum_p = ctx_p + (size_t)8 * 64 * 4096;             // [8,64,64]   (still in xb)

    // 1) fused prep: x -> bf16, W_qkv -> bf16 transposed (one dispatch)
    prep_kernel<<<16384 + 3072, 256, 0, stream>>>(x, xb, W_qkv, wqT);

    // 2) QKV GEMM -> Q / K / V bf16 (fused Q softmax epilogue)
    gemm_qkv_kernel<<<dim3(QKV3 / 256, TOKENS / 256), 512, 0, stream>>>(
        xb, CC, wqT, CC, b_qkv, Qm, Km, Vm);

    // 3) single-pass exp(K)/V -> per-chunk partials (no atomics)
    kv_ctx_kernel<<<dim3(BBATCH * HH, 8), 256, 0, stream>>>(Km, Vm, ctx_p, csum_p);

    // 4) effective projection weights per batch (fused partial-reduce + 1/csum)
    weff_kernel<<<dim3(BBATCH * HH, 8), 256, 0, stream>>>(
        ctx_p, csum_p, W_proj, WeffT);

    // 5) out = Qhat @ WeffT[batch] + b_proj (256^2 8-phase, 1 block/CU)
    gemm_out_kernel<<<dim3(CC / 256, TOKENS / 256), 512, 0, stream>>>(
        Qm, CC, WeffT, CC, b_proj, out, CC);
}